// Round 1
// 988.542 us; speedup vs baseline: 1.0318x; 1.0318x over previous
//
#include <hip/hip_runtime.h>
#include <math.h>
#include <stdint.h>

#define N_C 60000
#define N_V 256
#define CH 128
#define NH 4
#define HD 32
#define NL 3
#define NE1 600000
#define NE2 240000

#define CDIV(a,b) (((a)+(b)-1)/(b))
#define EPB 1024   // elems per block in counting-sort kernels

__device__ __forceinline__ float gelu_tanh(float x) {
    float x3 = x * x * x;
    float t = tanhf(0.7978845608028654f * (x + 0.044715f * x3));
    return 0.5f * x * (1.0f + t);
}

__device__ __forceinline__ float dot8(float4 qa, float4 qb, float4 ka, float4 kb) {
    float d = qa.x * ka.x;
    d = fmaf(qa.y, ka.y, d);
    d = fmaf(qa.z, ka.z, d);
    d = fmaf(qa.w, ka.w, d);
    d = fmaf(qb.x, kb.x, d);
    d = fmaf(qb.y, kb.y, d);
    d = fmaf(qb.z, kb.z, d);
    d = fmaf(qb.w, kb.w, d);
    return d;
}

// ---------------- weight composition: W~q = Wq . arel  (prel/sqrt(D) folded) ---
__global__ __launch_bounds__(256) void compose_wq(
    const float* __restrict__ Wq, const float* __restrict__ bq,
    const float* __restrict__ arel, const float* __restrict__ prel,
    float* __restrict__ WQT, float* __restrict__ BQT)
{
    int gid = blockIdx.x * blockDim.x + threadIdx.x;
    const int total = NL * 2 * (CH + 1) * CH;
    if (gid >= total) return;
    int li2 = gid / ((CH + 1) * CH);
    int rem = gid % ((CH + 1) * CH);
    int c   = rem / CH;          // 0..CH ; CH => bias row
    int col = rem % CH;
    int h = col >> 5, d = col & 31;
    const float* ar = arel + (li2 * NH + h) * (HD * HD) + d * HD;  // [e]
    float scale = prel[li2 * NH + h] * 0.17677669529663687f;       // prel/sqrt(32)
    const float* src = (c < CH) ? (Wq + ((size_t)li2 * CH + c) * CH + h * HD)
                                : (bq + li2 * CH + h * HD);
    float acc = 0.f;
    #pragma unroll
    for (int e = 0; e < HD; e++) acc = fmaf(src[e], ar[e], acc);
    acc *= scale;
    if (c < CH) WQT[((size_t)li2 * CH + c) * CH + col] = acc;
    else        BQT[li2 * CH + col] = acc;
}

// ================= CSR build: two-level LDS counting sort =====================
__global__ __launch_bounds__(256) void bucket_hist(const int* __restrict__ dst, int E,
                                                   int shift, int* __restrict__ bhist)
{
    __shared__ int h[256];
    int t = threadIdx.x;
    h[t] = 0;
    __syncthreads();
    int i0 = blockIdx.x * EPB, i1 = min(i0 + EPB, E);
    for (int i = i0 + t; i < i1; i += 256)
        atomicAdd(&h[(dst[i] >> shift) & 255], 1);
    __syncthreads();
    if (h[t] > 0) atomicAdd(&bhist[t], h[t]);
}

__global__ __launch_bounds__(256) void scan256(const int* __restrict__ h,
                                               int* __restrict__ base, int* __restrict__ cur)
{
    __shared__ int p[256];
    int t = threadIdx.x;
    int v = h[t];
    p[t] = v;
    __syncthreads();
    for (int off = 1; off < 256; off <<= 1) {
        int u = (t >= off) ? p[t - off] : 0;
        __syncthreads();
        p[t] += u;
        __syncthreads();
    }
    base[t] = p[t] - v;
    cur[t]  = p[t] - v;
    if (t == 255) base[256] = p[255];
}

template<bool PAIR>
__global__ __launch_bounds__(256) void partition_edges(
    const int* __restrict__ src, const int* __restrict__ dst, int E, int shift,
    int* __restrict__ cur, int2* __restrict__ tmp_pair, int* __restrict__ out_src)
{
    __shared__ int cnt[256], base[256], cnt2[256];
    int t = threadIdx.x;
    cnt[t] = 0; cnt2[t] = 0;
    __syncthreads();
    int i0 = blockIdx.x * EPB, i1 = min(i0 + EPB, E);
    for (int i = i0 + t; i < i1; i += 256)
        atomicAdd(&cnt[(dst[i] >> shift) & 255], 1);
    __syncthreads();
    if (cnt[t] > 0) base[t] = atomicAdd(&cur[t], cnt[t]);
    __syncthreads();
    for (int i = i0 + t; i < i1; i += 256) {
        int d = dst[i];
        int dig = (d >> shift) & 255;
        int r = atomicAdd(&cnt2[dig], 1);
        int pos = base[dig] + r;
        if constexpr (PAIR) tmp_pair[pos] = make_int2(src[i], d);
        else                out_src[pos] = src[i];
    }
}

__global__ __launch_bounds__(256) void bucket_finalize(
    const int2* __restrict__ tmp, const int* __restrict__ bbase, int n, int NE,
    int* __restrict__ rs, int* __restrict__ csr)
{
    __shared__ int cnt[256], pre[256], cnt2[256];
    int b = blockIdx.x, t = threadIdx.x;
    int s0 = bbase[b], s1 = bbase[b + 1];
    cnt[t] = 0; cnt2[t] = 0;
    __syncthreads();
    for (int i = s0 + t; i < s1; i += 256)
        atomicAdd(&cnt[tmp[i].y & 255], 1);
    __syncthreads();
    int v = cnt[t];
    pre[t] = v;
    __syncthreads();
    for (int off = 1; off < 256; off <<= 1) {
        int u = (t >= off) ? pre[t - off] : 0;
        __syncthreads();
        pre[t] += u;
        __syncthreads();
    }
    pre[t] -= v;   // exclusive
    __syncthreads();
    int dstid = b * 256 + t;
    if (dstid < n) rs[dstid] = s0 + pre[t];
    if (b == 0 && t == 0) rs[n] = NE;
    for (int i = s0 + t; i < s1; i += 256) {
        int2 e = tmp[i];
        int low = e.y & 255;
        int r = atomicAdd(&cnt2[low], 1);
        csr[s0 + pre[low] + r] = e.x;
    }
}

// ---------------- fused q~/k/v GEMM + tail blocks run prev-layer attn_out ------
__global__ __launch_bounds__(256) void gemm_qkv(
    int nblk1,
    const float* __restrict__ A, int lda, int M,
    const float* __restrict__ W0, const float* __restrict__ W1, const float* __restrict__ W2,
    const float* __restrict__ b0, const float* __restrict__ b1, const float* __restrict__ b2,
    float* __restrict__ out,
    // prev-layer out-conv attention (tail blocks); unused when grid == nblk1
    const float* __restrict__ qo, const float* __restrict__ ko, const float* __restrict__ vo,
    const int* __restrict__ rs_cv, const int* __restrict__ csr_cv,
    const float* __restrict__ arel_o, const float* __restrict__ prel_o,
    const float* __restrict__ mrel_o, const float* __restrict__ Wa_o,
    const float* __restrict__ ba_o, float* __restrict__ outl)
{
    __shared__ float As[64][132];   // 33 KB
    __shared__ float Bs[32][128];   // 16 KB
    __shared__ float sms[4], sma[4];
    int tid = threadIdx.x;

    if ((int)blockIdx.x >= nblk1) {
        // ---------------- prev-layer out-conv scalar attention ----------------
        int node = blockIdx.x - nblk1;
        float qs = qo[node] * arel_o[0] * prel_o[0];
        int rs = rs_cv[node], re = rs_cv[node + 1];
        float s = 0.f, a = 0.f;
        for (int e = rs + tid; e < re; e += 256) {
            int si = csr_cv[e];
            float w = __expf(qs * ko[si]);
            s += w;
            a = fmaf(w, vo[si], a);
        }
        #pragma unroll
        for (int off = 32; off >= 1; off >>= 1) {
            s += __shfl_xor(s, off, 64);
            a += __shfl_xor(a, off, 64);
        }
        int lane = tid & 63, wid = tid >> 6;
        if (lane == 0) { sms[wid] = s; sma[wid] = a; }
        __syncthreads();
        if (tid == 0) {
            float S = sms[0] + sms[1] + sms[2] + sms[3];
            float A_ = sma[0] + sma[1] + sma[2] + sma[3];
            float agg = (S > 0.f) ? A_ / S : 0.f;
            agg *= mrel_o[0];
            outl[node] = gelu_tanh(agg) * Wa_o[0] + ba_o[0];
        }
        return;
    }

    int row0 = blockIdx.x * 64;
    int tx = tid & 15;   // cols tx*4..+3 and 64+tx*4..+3
    int ty = tid >> 4;   // rows ty*4..+3
    #pragma unroll
    for (int i = 0; i < 8; i++) {
        int slot = tid + i * 256;            // [0,2048) float4 slots
        int r = slot >> 5, kq = slot & 31;
        int rr = row0 + r;
        float4 v = make_float4(0.f, 0.f, 0.f, 0.f);
        if (rr < M) v = *(const float4*)(A + (size_t)rr * lda + kq * 4);
        *(float4*)&As[r][kq * 4] = v;
    }
    const float* Ws[3] = {W0, W1, W2};
    const float* bs[3] = {b0, b1, b2};
    for (int jw = 0; jw < 3; jw++) {
        float acc[4][8] = {};
        for (int k0 = 0; k0 < 128; k0 += 32) {
            __syncthreads();
            #pragma unroll
            for (int i = 0; i < 4; i++) {
                int slot = tid + i * 256;    // [0,1024)
                int kr = slot >> 5, cq = slot & 31;
                *(float4*)&Bs[kr][cq * 4] = *(const float4*)(Ws[jw] + (size_t)(k0 + kr) * 128 + cq * 4);
            }
            __syncthreads();
            #pragma unroll
            for (int k4 = 0; k4 < 32; k4 += 4) {
                float4 av[4];
                #pragma unroll
                for (int i = 0; i < 4; i++)
                    av[i] = *(const float4*)&As[ty * 4 + i][k0 + k4];
                #pragma unroll
                for (int kk = 0; kk < 4; kk++) {
                    float4 bl = *(const float4*)&Bs[k4 + kk][tx * 4];
                    float4 bh = *(const float4*)&Bs[k4 + kk][64 + tx * 4];
                    float bb[8] = {bl.x, bl.y, bl.z, bl.w, bh.x, bh.y, bh.z, bh.w};
                    #pragma unroll
                    for (int i = 0; i < 4; i++) {
                        float a = ((const float*)&av[i])[kk];
                        #pragma unroll
                        for (int j = 0; j < 8; j++)
                            acc[i][j] = fmaf(a, bb[j], acc[i][j]);
                    }
                }
            }
        }
        #pragma unroll
        for (int i = 0; i < 4; i++) {
            int r = row0 + ty * 4 + i;
            if (r >= M) continue;
            float4 o0 = make_float4(acc[i][0] + bs[jw][tx * 4 + 0],
                                    acc[i][1] + bs[jw][tx * 4 + 1],
                                    acc[i][2] + bs[jw][tx * 4 + 2],
                                    acc[i][3] + bs[jw][tx * 4 + 3]);
            float4 o1 = make_float4(acc[i][4] + bs[jw][64 + tx * 4 + 0],
                                    acc[i][5] + bs[jw][64 + tx * 4 + 1],
                                    acc[i][6] + bs[jw][64 + tx * 4 + 2],
                                    acc[i][7] + bs[jw][64 + tx * 4 + 3]);
            float* op = out + (size_t)r * 384 + jw * 128;
            *(float4*)(op + tx * 4) = o0;
            *(float4*)(op + 64 + tx * 4) = o1;
        }
    }
}

// ---------------- fp32 GEMM, split cols, + fused scalar projections ------------
// Merged dual dispatch: blocks [0,nblk1) run GEMM-1 (c-side), blocks >= nblk1
// run GEMM-2 (v-side). All parameter selection is wave-uniform.
__global__ __launch_bounds__(256) void gemm128(
    int nblk1,
    // primary (c-side)
    const float* __restrict__ A1, int lda1, const float* __restrict__ W1,
    const float* __restrict__ bias1, float* __restrict__ out1, int M1,
    const float* __restrict__ gate1, const float* __restrict__ xold1,
    const float* __restrict__ wk1, const float* __restrict__ bk1, float* __restrict__ ko1,
    const float* __restrict__ wv1, const float* __restrict__ bv1, float* __restrict__ vo1,
    // secondary (v-side)
    const float* __restrict__ A2, int lda2, const float* __restrict__ W2,
    const float* __restrict__ bias2, float* __restrict__ out2, int M2,
    const float* __restrict__ gate2, const float* __restrict__ xold2,
    const float* __restrict__ wk2, const float* __restrict__ bk2, float* __restrict__ ko2)
{
    __shared__ float As[64][36];    // 9 KB (32-wide k-tile, +4 pad)
    __shared__ float Bs[32][128];   // 16 KB
    bool sec = (blockIdx.x >= (unsigned)nblk1);
    const float* A    = sec ? A2 : A1;
    int lda           = sec ? lda2 : lda1;
    const float* W    = sec ? W2 : W1;
    const float* bias = sec ? bias2 : bias1;
    float* out        = sec ? out2 : out1;
    int M             = sec ? M2 : M1;
    const float* gate = sec ? gate2 : gate1;
    const float* xold = sec ? xold2 : xold1;
    const float* wk_o = sec ? wk2 : wk1;
    const float* bk_o = sec ? bk2 : bk1;
    float* ko         = sec ? ko2 : ko1;
    const float* wv_o = sec ? nullptr : wv1;
    const float* bv_o = sec ? nullptr : bv1;
    float* vo         = sec ? nullptr : vo1;

    int tid = threadIdx.x;
    int row0 = (sec ? (blockIdx.x - nblk1) : blockIdx.x) * 64;
    int tx = tid & 15;
    int ty = tid >> 4;
    float acc[4][8] = {};
    for (int k0 = 0; k0 < 128; k0 += 32) {
        __syncthreads();
        #pragma unroll
        for (int i = 0; i < 2; i++) {
            int slot = tid + i * 256;            // [0,512) float4 slots
            int r = slot >> 3, kq = slot & 7;
            int rr = row0 + r;
            float4 v = make_float4(0.f, 0.f, 0.f, 0.f);
            if (rr < M) v = *(const float4*)(A + (size_t)rr * lda + k0 + kq * 4);
            *(float4*)&As[r][kq * 4] = v;
        }
        #pragma unroll
        for (int i = 0; i < 4; i++) {
            int slot = tid + i * 256;            // [0,1024)
            int kr = slot >> 5, cq = slot & 31;
            *(float4*)&Bs[kr][cq * 4] = *(const float4*)(W + (size_t)(k0 + kr) * 128 + cq * 4);
        }
        __syncthreads();
        #pragma unroll
        for (int k4 = 0; k4 < 32; k4 += 4) {
            float4 av[4];
            #pragma unroll
            for (int i = 0; i < 4; i++)
                av[i] = *(const float4*)&As[ty * 4 + i][k4];
            #pragma unroll
            for (int kk = 0; kk < 4; kk++) {
                float4 bl = *(const float4*)&Bs[k4 + kk][tx * 4];
                float4 bh = *(const float4*)&Bs[k4 + kk][64 + tx * 4];
                float bb[8] = {bl.x, bl.y, bl.z, bl.w, bh.x, bh.y, bh.z, bh.w};
                #pragma unroll
                for (int i = 0; i < 4; i++) {
                    float a = ((const float*)&av[i])[kk];
                    #pragma unroll
                    for (int j = 0; j < 8; j++)
                        acc[i][j] = fmaf(a, bb[j], acc[i][j]);
                }
            }
        }
    }
    float g = 1.f, og = 0.f;
    if (gate != nullptr) { g = 1.f / (1.f + expf(-gate[0])); og = 1.f - g; }
    float wkr[8], wvr[8];
    if (wk_o != nullptr) {
        #pragma unroll
        for (int j = 0; j < 4; j++) {
            wkr[j]     = wk_o[tx * 4 + j];
            wkr[4 + j] = wk_o[64 + tx * 4 + j];
        }
    }
    if (wv_o != nullptr) {
        #pragma unroll
        for (int j = 0; j < 4; j++) {
            wvr[j]     = wv_o[tx * 4 + j];
            wvr[4 + j] = wv_o[64 + tx * 4 + j];
        }
    }
    #pragma unroll
    for (int i = 0; i < 4; i++) {
        int r = row0 + ty * 4 + i;
        if (r >= M) continue;   // uniform across each 16-lane group
        float vals[8];
        #pragma unroll
        for (int j = 0; j < 4; j++) {
            float v0 = acc[i][j]     + bias[tx * 4 + j];
            float v1 = acc[i][4 + j] + bias[64 + tx * 4 + j];
            if (gate != nullptr) {
                v0 = g * v0 + og * xold[(size_t)r * 128 + tx * 4 + j];
                v1 = g * v1 + og * xold[(size_t)r * 128 + 64 + tx * 4 + j];
            }
            vals[j] = v0;
            vals[4 + j] = v1;
        }
        float* op = out + (size_t)r * 128;
        *(float4*)(op + tx * 4)      = make_float4(vals[0], vals[1], vals[2], vals[3]);
        *(float4*)(op + 64 + tx * 4) = make_float4(vals[4], vals[5], vals[6], vals[7]);
        if (wk_o != nullptr) {
            float pk = 0.f, pv = 0.f;
            #pragma unroll
            for (int j = 0; j < 8; j++) pk = fmaf(vals[j], wkr[j], pk);
            if (wv_o != nullptr) {
                #pragma unroll
                for (int j = 0; j < 8; j++) pv = fmaf(vals[j], wvr[j], pv);
            }
            #pragma unroll
            for (int off = 1; off < 16; off <<= 1) {
                pk += __shfl_xor(pk, off, 64);
                if (wv_o != nullptr) pv += __shfl_xor(pv, off, 64);
            }
            if (tx == 0) {
                ko[r] = pk + bk_o[0];
                if (wv_o != nullptr) vo[r] = pv + bv_o[0];
            }
        }
    }
}

// ---------------- pipelined edge accumulation --------------------------------
// Per 64-edge chunk: one wave-coalesced csr load, indices distributed via shfl
// (no per-iteration csr round trip); k/v gathers register-double-buffered with
// a 2-round unrolled loop so the next round's loads are in flight during the
// current round's dot/exp/FMA work. Out-of-range slots load a clamped (n-1)
// address (L1 hit on a line the wave fetches anyway) and are masked via w=0.
__device__ __forceinline__ void gather_pipe(
    const float* __restrict__ xqkv, const int* __restrict__ csr,
    int e0, int e1, int g, int j, float4 qa, float4 qb,
    float& s_io, float acc[8])
{
    int lane = threadIdx.x & 63;
    float s = s_io;
    for (int cs = e0; cs < e1; cs += 64) {
        int n = e1 - cs; if (n > 64) n = 64;
        int nm1 = n - 1;
        int idx0 = 0;
        if (lane < n) idx0 = csr[cs + lane];
        int R = (n + 7) >> 3;   // rounds of 8 edges (2 per group)

        float4 aka, akb, ava, avb, bka, bkb, bva, bvb;   // buffer A (even rounds)
        float4 cka, ckb, cva, cvb, dka, dkb, dva, dvb;   // buffer B (odd rounds)

#define LD2(E0_, E1_, KA, KB, VA, VB, KC, KD, VC, VD) { \
            int i0_ = __shfl(idx0, min((E0_), nm1), 64); \
            int i1_ = __shfl(idx0, min((E1_), nm1), 64); \
            const float* p0_ = xqkv + (size_t)i0_ * 384 + 128 + 8 * j; \
            const float* p1_ = xqkv + (size_t)i1_ * 384 + 128 + 8 * j; \
            KA = *(const float4*)p0_;         KB = *(const float4*)(p0_ + 4); \
            VA = *(const float4*)(p0_ + 128); VB = *(const float4*)(p0_ + 132); \
            KC = *(const float4*)p1_;         KD = *(const float4*)(p1_ + 4); \
            VC = *(const float4*)(p1_ + 128); VD = *(const float4*)(p1_ + 132); }

#define CMP(E0_, E1_, KA, KB, VA, VB, KC, KD, VC, VD) { \
            float d0_ = dot8(qa, qb, KA, KB); \
            float d1_ = dot8(qa, qb, KC, KD); \
            d0_ += __shfl_xor(d0_, 1, 64); d1_ += __shfl_xor(d1_, 1, 64); \
            d0_ += __shfl_xor(d0_, 2, 64); d1_ += __shfl_xor(d1_, 2, 64); \
            float w0_ = ((E0_) < n) ? __expf(d0_) : 0.f; \
            float w1_ = ((E1_) < n) ? __expf(d1_) : 0.f; \
            s += w0_ + w1_; \
            acc[0] = fmaf(w0_, VA.x, acc[0]); acc[0] = fmaf(w1_, VC.x, acc[0]); \
            acc[1] = fmaf(w0_, VA.y, acc[1]); acc[1] = fmaf(w1_, VC.y, acc[1]); \
            acc[2] = fmaf(w0_, VA.z, acc[2]); acc[2] = fmaf(w1_, VC.z, acc[2]); \
            acc[3] = fmaf(w0_, VA.w, acc[3]); acc[3] = fmaf(w1_, VC.w, acc[3]); \
            acc[4] = fmaf(w0_, VB.x, acc[4]); acc[4] = fmaf(w1_, VD.x, acc[4]); \
            acc[5] = fmaf(w0_, VB.y, acc[5]); acc[5] = fmaf(w1_, VD.y, acc[5]); \
            acc[6] = fmaf(w0_, VB.z, acc[6]); acc[6] = fmaf(w1_, VD.z, acc[6]); \
            acc[7] = fmaf(w0_, VB.w, acc[7]); acc[7] = fmaf(w1_, VD.w, acc[7]); }

        // prefetch round 0 (A) and round 1 (B)
        LD2(g, g + 4, aka, akb, ava, avb, bka, bkb, bva, bvb);
        if (R > 1) LD2(g + 8, g + 12, cka, ckb, cva, cvb, dka, dkb, dva, dvb);

        for (int r = 0; r < R; r += 2) {
            int er = g + 8 * r;
            CMP(er, er + 4, aka, akb, ava, avb, bka, bkb, bva, bvb);
            if (r + 2 < R) {
                int ep = g + 8 * (r + 2);
                LD2(ep, ep + 4, aka, akb, ava, avb, bka, bkb, bva, bvb);
            }
            if (r + 1 < R) {
                int eo = g + 8 * (r + 1);
                CMP(eo, eo + 4, cka, ckb, cva, cvb, dka, dkb, dva, dvb);
                if (r + 3 < R) {
                    int eq = g + 8 * (r + 3);
                    LD2(eq, eq + 4, cka, ckb, cva, cvb, dka, dkb, dva, dvb);
                }
            }
        }
#undef LD2
#undef CMP
    }
    s_io = s;
}

// ---------------- unified attention: cv blocks [0,256) + cc blocks -------------
__global__ __launch_bounds__(256) void attn_uni(
    float* xqkv,
    const float* __restrict__ xv, const float* __restrict__ wqt,
    const float* __restrict__ bqt,
    const int* __restrict__ rs_cc, const int* __restrict__ csr_cc,
    const int* __restrict__ rs_cv, const int* __restrict__ csr_cv,
    const float* __restrict__ mrel_cc, const float* __restrict__ mrel_cv,
    float* __restrict__ aggv, int n_c)
{
    __shared__ float smem[800];   // 3.2 KB, carved per role
    int lane = threadIdx.x & 63, wid = threadIdx.x >> 6;
    int g = lane >> 4, j = lane & 15;

    if (blockIdx.x < N_V) {
        // ---------------- cv node ----------------
        int node = blockIdx.x;
        float* qrow = smem;          // [128]
        float* sm_s = smem + 128;    // [4][4]
        float* sm_a = smem + 144;    // [4][128]
        float* orow = smem + 656;    // [144]
        if (wid < 2) {
            int col = wid * 64 + lane;
            float a = bqt[col];
            const float* xr = xv + (size_t)node * 128;
            for (int k = 0; k < 128; k++)
                a = fmaf(xr[k], wqt[(size_t)k * 128 + col], a);
            qrow[col] = a;
        }
        __syncthreads();
        float4 qa = *(const float4*)&qrow[8 * j];
        float4 qb = *(const float4*)&qrow[8 * j + 4];
        int rs = rs_cv[node], re = rs_cv[node + 1];
        int cnt = re - rs;
        int per = (cnt + 3) >> 2;
        int e0 = rs + wid * per, e1 = min(e0 + per, re);
        float s = 0.f;
        float acc[8] = {};
        gather_pipe(xqkv, csr_cv, e0, e1, g, j, qa, qb, s, acc);
        #pragma unroll
        for (int i = 0; i < 8; i++) {
            acc[i] += __shfl_xor(acc[i], 16, 64);
            acc[i] += __shfl_xor(acc[i], 32, 64);
        }
        s += __shfl_xor(s, 16, 64);
        s += __shfl_xor(s, 32, 64);
        if (g == 0) {
            *(float4*)&sm_a[wid * 128 + 8 * j]     = make_float4(acc[0], acc[1], acc[2], acc[3]);
            *(float4*)&sm_a[wid * 128 + 8 * j + 4] = make_float4(acc[4], acc[5], acc[6], acc[7]);
            if ((j & 3) == 0) sm_s[wid * 4 + (j >> 2)] = s;
        }
        __syncthreads();
        if (threadIdx.x < 64) {
            int lp = 2 * lane;
            int h = lp >> 5;
            float S = 0.f, AX = 0.f, AY = 0.f;
            #pragma unroll
            for (int i = 0; i < 4; i++) {
                S  += sm_s[i * 4 + h];
                float2 a2 = *(const float2*)&sm_a[i * 128 + lp];
                AX += a2.x;
                AY += a2.y;
            }
            float inv = (S > 0.f) ? 1.f / S : 0.f;
            int off = lp + 4 * h;   // padded
            orow[off]     = AX * inv;
            orow[off + 1] = AY * inv;
            int eo = lp & 31;
            const float* mr = mrel_cv + h * 1024 + eo;
            const float* rb = orow + 36 * h;
            float t0 = 0.f, t1 = 0.f;
            #pragma unroll
            for (int d = 0; d < 32; d++) {
                float a = rb[d];
                t0 = fmaf(a, mr[d * 32], t0);
                t1 = fmaf(a, mr[d * 32 + 1], t1);
            }
            aggv[(size_t)node * 128 + lp]     = gelu_tanh(t0);
            aggv[(size_t)node * 128 + lp + 1] = gelu_tanh(t1);
        }
    } else {
        // ---------------- cc nodes (4 per block, 1 wave each) ----------------
        float* rowbuf = smem;        // [4][144]
        int node = (blockIdx.x - N_V) * 4 + wid;
        if (node >= n_c) return;
        const float* qp = xqkv + (size_t)node * 384 + 8 * j;
        float4 qa = *(const float4*)qp, qb = *(const float4*)(qp + 4);
        int rs = rs_cc[node], re = rs_cc[node + 1];
        float s = 0.f;
        float acc[8] = {};
        gather_pipe(xqkv, csr_cc, rs, re, g, j, qa, qb, s, acc);
        #pragma unroll
        for (int i = 0; i < 8; i++) {
            acc[i] += __shfl_xor(acc[i], 16, 64);
            acc[i] += __shfl_xor(acc[i], 32, 64);
        }
        s += __shfl_xor(s, 16, 64);
        s += __shfl_xor(s, 32, 64);
        float inv = (s > 0.f) ? 1.f / s : 0.f;
        float* rb_w = rowbuf + wid * 144;
        if (g == 0) {
            int off = 8 * j + 4 * (j >> 2);   // +4 pad per head
            float4 o0 = make_float4(acc[0] * inv, acc[1] * inv, acc[2] * inv, acc[3] * inv);
            float4 o1 = make_float4(acc[4] * inv, acc[5] * inv, acc[6] * inv, acc[7] * inv);
            *(float4*)&rb_w[off]     = o0;
            *(float4*)&rb_w[off + 4] = o1;
        }
        // intra-wave DS ordering: no barrier needed
        int lp = 2 * lane;
        int h = lp >> 5, eo = lp & 31;
        const float* mr = mrel_cc + h * 1024 + eo;
        const float* rb = rb_w + 36 * h;
        float t0 = 0.f, t1 = 0.f;
        #pragma unroll
        for (int d = 0; d < 32; d++) {
            float a = rb[d];
            t0 = fmaf(a, mr[d * 32], t0);
            t1 = fmaf(a, mr[d * 32 + 1], t1);
        }
        float2 o = make_float2(gelu_tanh(t0), gelu_tanh(t1));
        *(float2*)(xqkv + (size_t)node * 384 + lp) = o;
    }
}

// ---------------- out-conv scalar attention (standalone, last layer) -----------
__global__ __launch_bounds__(256) void attn_out(
    const float* __restrict__ qo, const float* __restrict__ ko, const float* __restrict__ vo,
    const int* __restrict__ rowstart, const int* __restrict__ csr,
    const float* __restrict__ arel_o, const float* __restrict__ prel_o,
    const float* __restrict__ mrel_o, const float* __restrict__ Wa_o,
    const float* __restrict__ ba_o, float* __restrict__ outl)
{
    int node = blockIdx.x;
    float qs = qo[node] * arel_o[0] * prel_o[0];
    int rs = rowstart[node], re = rowstart[node + 1];
    float s = 0.f, a = 0.f;
    for (int e = rs + (int)threadIdx.x; e < re; e += 256) {
        int si = csr[e];
        float w = __expf(qs * ko[si]);
        s += w;
        a = fmaf(w, vo[si], a);
    }
    #pragma unroll
    for (int off = 32; off >= 1; off >>= 1) {
        s += __shfl_xor(s, off, 64);
        a += __shfl_xor(a, off, 64);
    }
    __shared__ float sms[4], sma[4];
    int lane = threadIdx.x & 63, wid = threadIdx.x >> 6;
    if (lane == 0) { sms[wid] = s; sma[wid] = a; }
    __syncthreads();
    if (threadIdx.x == 0) {
        float S = sms[0] + sms[1] + sms[2] + sms[3];
        float A = sma[0] + sma[1] + sma[2] + sma[3];
        float agg = (S > 0.f) ? A / S : 0.f;
        agg *= mrel_o[0];
        outl[node] = gelu_tanh(agg) * Wa_o[0] + ba_o[0];
    }
}

// ---------------- final head: JK-max -> node_fc -> MLP ------------------------
__global__ void final_head(const float* __restrict__ outs,
    const float* __restrict__ fc_W, const float* __restrict__ fc_b,
    const float* __restrict__ W1, const float* __restrict__ b1,
    const float* __restrict__ W2, const float* __restrict__ b2,
    float* __restrict__ out)
{
    int b = threadIdx.x;
    if (b >= 64) return;
    float h = fc_b[0];
    #pragma unroll
    for (int v = 0; v < 4; v++) {
        int n = b * 4 + v;
        float jk = fmaxf(fmaxf(outs[0 * N_V + n], outs[1 * N_V + n]), outs[2 * N_V + n]);
        h = fmaf(jk, fc_W[v], h);
    }
    h = gelu_tanh(h);
    float h0 = gelu_tanh(h * W1[0] + b1[0]);
    float h1 = gelu_tanh(h * W1[1] + b1[1]);
    out[b] = h0 * W2[0] + h1 * W2[1] + b2[0];
}

// ---------------- orchestration ----------------------------------------------
extern "C" void kernel_launch(void* const* d_in, const int* in_sizes, int n_in,
                              void* d_out, int out_size, void* d_ws, size_t ws_size,
                              hipStream_t stream) {
    (void)in_sizes; (void)n_in; (void)out_size; (void)ws_size;
    const float* x_cell  = (const float*)d_in[0];
    const float* x_vcell = (const float*)d_in[1];
    const float* Wk   = (const float*)d_in[2];
    const float* bk   = (const float*)d_in[3];
    const float* Wq   = (const float*)d_in[4];
    const float* bq   = (const float*)d_in[5];
    const float* Wv   = (const float*)d_in[6];
    const float* bv   = (const float*)d_in[7];
    const float* Wa   = (const float*)d_in[8];
    const float* ba   = (const float*)d_in[9];
    const float* skip = (const float*)d_in[10];
    const float* arel = (const float*)d_in[11];
    const float* mrel = (const float*)d_in[12];
    const float* prel = (const float*)d_in[13];
    const float* Wk_o = (const float*)d_in[14];
    const float* bk_o = (const float*)d_in[15];
    const float* Wq_o = (const float*)d_in[16];
    const float* bq_o = (const float*)d_in[17];
    const float* Wv_o = (const float*)d_in[18];
    const float* bv_o = (const float*)d_in[19];
    const float* Wa_o = (const float*)d_in[20];
    const float* ba_o = (const float*)d_in[21];
    const float* arel_o = (const float*)d_in[22];
    const float* mrel_o = (const float*)d_in[23];
    const float* prel_o = (const float*)d_in[24];
    const float* fc_W  = (const float*)d_in[25];
    const float* fc_b  = (const float*)d_in[26];
    const float* mlp_W1 = (const float*)d_in[27];
    const float* mlp_b1 = (const float*)d_in[28];
    const float* mlp_W2 = (const float*)d_in[29];
    const float* mlp_b2 = (const float*)d_in[30];
    const int* src_cc = (const int*)d_in[31];
    const int* dst_cc = (const int*)d_in[32];
    const int* src_cv = (const int*)d_in[33];
    const int* dst_cv = (const int*)d_in[34];

    // workspace carve-up (256B aligned)
    char* p = (char*)d_ws;
    auto alloc = [&](size_t bytes) -> char* {
        uintptr_t q = ((uintptr_t)p + 255) & ~(uintptr_t)255;
        p = (char*)(q + bytes);
        return (char*)q;
    };
    float* WQT  = (float*)alloc(sizeof(float) * NL * 2 * CH * CH);
    float* BQT  = (float*)alloc(sizeof(float) * NL * 2 * CH);
    float* XC   = (float*)alloc(sizeof(float) * (size_t)N_C * CH);
    float* XV   = (float*)alloc(sizeof(float) * (size_t)N_V * CH);
    float* XQKV = (float*)alloc(sizeof(float) * (size_t)N_C * 384);  // [q~|k|v] per node
    float* AGGV = (float*)alloc(sizeof(float) * (size_t)N_V * CH);
    float* KO   = (float*)alloc(sizeof(float) * N_C);
    float* VO   = (float*)alloc(sizeof(float) * N_C);
    float* QO   = (float*)alloc(sizeof(float) * N_V);
    float* OUTS = (float*)alloc(sizeof(float) * NL * N_V);
    // CSR-build scratch (hist region zeroed in one memset)
    int* bhist    = (int*)alloc(sizeof(int) * 512);
    int* bhist_cc = bhist;
    int* bhist_cv = bhist + 256;
    int* bbase_cc = (int*)alloc(sizeof(int) * 257);
    int* cur_cc   = (int*)alloc(sizeof(int) * 256);
    int* cur_cv   = (int*)alloc(sizeof(int) * 256);
    int* rs_cc    = (int*)alloc(sizeof(int) * (N_C + 1));
    int* rs_cv    = (int*)alloc(sizeof(int) * (N_V + 1));
    int* csr_cc   = (int*)alloc(sizeof(int) * NE1);
    int* csr_cv   = (int*)alloc(sizeof(int) * NE2);
    int2* tmp_cc  = (int2*)alloc(sizeof(int2) * NE1);

    // ---- setup: composed weights + CSR (two-level counting sort) ----
    compose_wq<<<CDIV(NL * 2 * (CH + 1) * CH, 256), 256, 0, stream>>>(
        Wq, bq, arel, prel, WQT, BQT);
    hipMemsetAsync(bhist, 0, sizeof(int) * 512, stream);
    bucket_hist<<<CDIV(NE1, EPB), 256, 0, stream>>>(dst_cc, NE1, 8, bhist_cc);
    bucket_hist<<<CDIV(NE2, EPB), 256, 0, stream>>>(dst_cv, NE2, 0, bhist_cv);
    scan256<<<1, 256, 0, stream>>>(bhist_cc, bbase_cc, cur_cc);
    scan256<<<1, 256, 0, stream>>>(bhist_cv, rs_cv, cur_cv);   // rs_cv IS the cv row starts
    partition_edges<true ><<<CDIV(NE1, EPB), 256, 0, stream>>>(src_cc, dst_cc, NE1, 8,
                                                               cur_cc, tmp_cc, nullptr);
    partition_edges<false><<<CDIV(NE2, EPB), 256, 0, stream>>>(src_cv, dst_cv, NE2, 0,
                                                               cur_cv, nullptr, csr_cv);
    bucket_finalize<<<CDIV(N_C, 256), 256, 0, stream>>>(tmp_cc, bbase_cc, N_C, NE1,
                                                        rs_cc, csr_cc);

    const int gb_c = CDIV(N_C, 64);             // 938
    const int gb_v = CDIV(N_V, 64);             // 4
    const int gb_attn = N_V + CDIV(N_C, 4);     // 256 cv + 15000 cc blocks

    for (int li = 0; li < NL; li++) {
        const float* xc_src = (li == 0) ? x_cell : XC;
        const float* xv_src = (li == 0) ? x_vcell : XV;
        size_t w0 = (size_t)(li * 2) * CH * CH;
        size_t w1 = (size_t)(li * 2 + 1) * CH * CH;
        int b0 = (li * 2) * CH, b1 = (li * 2 + 1) * CH;

        // fused q~/k/v GEMM; layers >0 append prev-layer out-conv attention tail
        int tail = (li > 0) ? N_V : 0;
        gemm_qkv<<<gb_c + tail, 256, 0, stream>>>(
            gb_c, xc_src, 128, N_C,
            WQT + w0, Wk + w0, Wv + w0,
            BQT + b0, bk + b0, bv + b0, XQKV,
            QO, KO, VO, rs_cv, csr_cv,
            arel_o + (li - 1), prel_o + (li - 1), mrel_o + (li - 1),
            Wa_o + (li - 1), ba_o + (li - 1),
            (li > 0) ? (OUTS + (li - 1) * N_V) : nullptr);

        // unified attention: cv (inline q~v projection, 4 waves/node) + cc
        attn_uni<<<gb_attn, 256, 0, stream>>>(
            XQKV, xv_src, WQT + w1, BQT + b1,
            rs_cc, csr_cc, rs_cv, csr_cv,
            mrel + (size_t)(li * 2) * NH * HD * HD,
            mrel + (size_t)(li * 2 + 1) * NH * HD * HD,
            AGGV, N_C);

        // merged Wa GEMMs (c-side + v-side in one dispatch) with skip epilogue;
        // c-side fuses out-conv k/v projections, v-side fuses q projection
        gemm128<<<gb_c + gb_v, 256, 0, stream>>>(
            gb_c,
            XQKV, 384, Wa + w0, ba + b0, XC, N_C,
            skip + li * 2, xc_src,
            Wk_o + li * CH, bk_o + li, KO,
            Wv_o + li * CH, bv_o + li, VO,
            AGGV, 128, Wa + w1, ba + b1, XV, N_V,
            skip + li * 2 + 1, xv_src,
            Wq_o + li * CH, bq_o + li, QO);
    }

    // last layer's out-conv attention, then final head
    attn_out<<<N_V, 256, 0, stream>>>(QO, KO, VO, rs_cv, csr_cv,
                                      arel_o + (NL - 1), prel_o + (NL - 1), mrel_o + (NL - 1),
                                      Wa_o + (NL - 1), ba_o + (NL - 1), OUTS + (NL - 1) * N_V);
    final_head<<<1, 64, 0, stream>>>(OUTS, fc_W, fc_b, mlp_W1, mlp_b1, mlp_W2, mlp_b2,
                                     (float*)d_out);
}

// Round 2
// 902.936 us; speedup vs baseline: 1.1296x; 1.0948x over previous
//
#include <hip/hip_runtime.h>
#include <hip/hip_fp16.h>
#include <math.h>
#include <stdint.h>

#define N_C 60000
#define N_V 256
#define CH 128
#define NH 4
#define HD 32
#define NL 3
#define NE1 600000
#define NE2 240000

#define CDIV(a,b) (((a)+(b)-1)/(b))
#define EPB 1024   // elems per block in counting-sort kernels

// XQKV record layout (per node, 1024 B stride = 256 floats):
//   bytes [0,512)    : q~ (layer in) / agg (layer out)  f32 x128
//   bytes [512,768)  : k   fp16 x128
//   bytes [768,1024) : v   fp16 x128

__device__ __forceinline__ float gelu_tanh(float x) {
    float x3 = x * x * x;
    float t = tanhf(0.7978845608028654f * (x + 0.044715f * x3));
    return 0.5f * x * (1.0f + t);
}

__device__ __forceinline__ void h8_to_f8(uint4 w, float* f) {
    float2 a = __half22float2(*(const __half2*)&w.x);
    float2 b = __half22float2(*(const __half2*)&w.y);
    float2 c = __half22float2(*(const __half2*)&w.z);
    float2 d = __half22float2(*(const __half2*)&w.w);
    f[0] = a.x; f[1] = a.y; f[2] = b.x; f[3] = b.y;
    f[4] = c.x; f[5] = c.y; f[6] = d.x; f[7] = d.y;
}

__device__ __forceinline__ float dot8f(const float* q, const float* k) {
    float d = q[0] * k[0];
    d = fmaf(q[1], k[1], d);
    d = fmaf(q[2], k[2], d);
    d = fmaf(q[3], k[3], d);
    d = fmaf(q[4], k[4], d);
    d = fmaf(q[5], k[5], d);
    d = fmaf(q[6], k[6], d);
    d = fmaf(q[7], k[7], d);
    return d;
}

// ---------------- weight composition: W~q = Wq . arel  (prel/sqrt(D) folded) ---
__global__ __launch_bounds__(256) void compose_wq(
    const float* __restrict__ Wq, const float* __restrict__ bq,
    const float* __restrict__ arel, const float* __restrict__ prel,
    float* __restrict__ WQT, float* __restrict__ BQT)
{
    int gid = blockIdx.x * blockDim.x + threadIdx.x;
    const int total = NL * 2 * (CH + 1) * CH;
    if (gid >= total) return;
    int li2 = gid / ((CH + 1) * CH);
    int rem = gid % ((CH + 1) * CH);
    int c   = rem / CH;          // 0..CH ; CH => bias row
    int col = rem % CH;
    int h = col >> 5, d = col & 31;
    const float* ar = arel + (li2 * NH + h) * (HD * HD) + d * HD;  // [e]
    float scale = prel[li2 * NH + h] * 0.17677669529663687f;       // prel/sqrt(32)
    const float* src = (c < CH) ? (Wq + ((size_t)li2 * CH + c) * CH + h * HD)
                                : (bq + li2 * CH + h * HD);
    float acc = 0.f;
    #pragma unroll
    for (int e = 0; e < HD; e++) acc = fmaf(src[e], ar[e], acc);
    acc *= scale;
    if (c < CH) WQT[((size_t)li2 * CH + c) * CH + col] = acc;
    else        BQT[li2 * CH + col] = acc;
}

// ================= CSR build: two-level LDS counting sort =====================
__global__ __launch_bounds__(256) void bucket_hist(const int* __restrict__ dst, int E,
                                                   int shift, int* __restrict__ bhist)
{
    __shared__ int h[256];
    int t = threadIdx.x;
    h[t] = 0;
    __syncthreads();
    int i0 = blockIdx.x * EPB, i1 = min(i0 + EPB, E);
    for (int i = i0 + t; i < i1; i += 256)
        atomicAdd(&h[(dst[i] >> shift) & 255], 1);
    __syncthreads();
    if (h[t] > 0) atomicAdd(&bhist[t], h[t]);
}

__global__ __launch_bounds__(256) void scan256(const int* __restrict__ h,
                                               int* __restrict__ base, int* __restrict__ cur)
{
    __shared__ int p[256];
    int t = threadIdx.x;
    int v = h[t];
    p[t] = v;
    __syncthreads();
    for (int off = 1; off < 256; off <<= 1) {
        int u = (t >= off) ? p[t - off] : 0;
        __syncthreads();
        p[t] += u;
        __syncthreads();
    }
    base[t] = p[t] - v;
    cur[t]  = p[t] - v;
    if (t == 255) base[256] = p[255];
}

template<bool PAIR>
__global__ __launch_bounds__(256) void partition_edges(
    const int* __restrict__ src, const int* __restrict__ dst, int E, int shift,
    int* __restrict__ cur, int2* __restrict__ tmp_pair, int* __restrict__ out_src)
{
    __shared__ int cnt[256], base[256], cnt2[256];
    int t = threadIdx.x;
    cnt[t] = 0; cnt2[t] = 0;
    __syncthreads();
    int i0 = blockIdx.x * EPB, i1 = min(i0 + EPB, E);
    for (int i = i0 + t; i < i1; i += 256)
        atomicAdd(&cnt[(dst[i] >> shift) & 255], 1);
    __syncthreads();
    if (cnt[t] > 0) base[t] = atomicAdd(&cur[t], cnt[t]);
    __syncthreads();
    for (int i = i0 + t; i < i1; i += 256) {
        int d = dst[i];
        int dig = (d >> shift) & 255;
        int r = atomicAdd(&cnt2[dig], 1);
        int pos = base[dig] + r;
        if constexpr (PAIR) tmp_pair[pos] = make_int2(src[i], d);
        else                out_src[pos] = src[i];
    }
}

__global__ __launch_bounds__(256) void bucket_finalize(
    const int2* __restrict__ tmp, const int* __restrict__ bbase, int n, int NE,
    int* __restrict__ rs, int* __restrict__ csr)
{
    __shared__ int cnt[256], pre[256], cnt2[256];
    int b = blockIdx.x, t = threadIdx.x;
    int s0 = bbase[b], s1 = bbase[b + 1];
    cnt[t] = 0; cnt2[t] = 0;
    __syncthreads();
    for (int i = s0 + t; i < s1; i += 256)
        atomicAdd(&cnt[tmp[i].y & 255], 1);
    __syncthreads();
    int v = cnt[t];
    pre[t] = v;
    __syncthreads();
    for (int off = 1; off < 256; off <<= 1) {
        int u = (t >= off) ? pre[t - off] : 0;
        __syncthreads();
        pre[t] += u;
        __syncthreads();
    }
    pre[t] -= v;   // exclusive
    __syncthreads();
    int dstid = b * 256 + t;
    if (dstid < n) rs[dstid] = s0 + pre[t];
    if (b == 0 && t == 0) rs[n] = NE;
    for (int i = s0 + t; i < s1; i += 256) {
        int2 e = tmp[i];
        int low = e.y & 255;
        int r = atomicAdd(&cnt2[low], 1);
        csr[s0 + pre[low] + r] = e.x;
    }
}

// ---------------- fused q~/k/v GEMM + tail blocks run prev-layer attn_out ------
// q~ stored f32; k,v stored fp16 (storage-only; math stays f32).
__global__ __launch_bounds__(256) void gemm_qkv(
    int nblk1,
    const float* __restrict__ A, int lda, int M,
    const float* __restrict__ W0, const float* __restrict__ W1, const float* __restrict__ W2,
    const float* __restrict__ b0, const float* __restrict__ b1, const float* __restrict__ b2,
    float* __restrict__ out,
    // prev-layer out-conv attention (tail blocks); unused when grid == nblk1
    const float* __restrict__ qo, const float* __restrict__ ko, const float* __restrict__ vo,
    const int* __restrict__ rs_cv, const int* __restrict__ csr_cv,
    const float* __restrict__ arel_o, const float* __restrict__ prel_o,
    const float* __restrict__ mrel_o, const float* __restrict__ Wa_o,
    const float* __restrict__ ba_o, float* __restrict__ outl)
{
    __shared__ float As[64][132];   // 33 KB
    __shared__ float Bs[32][128];   // 16 KB
    __shared__ float sms[4], sma[4];
    int tid = threadIdx.x;

    if ((int)blockIdx.x >= nblk1) {
        // ---------------- prev-layer out-conv scalar attention ----------------
        int node = blockIdx.x - nblk1;
        float qs = qo[node] * arel_o[0] * prel_o[0];
        int rs = rs_cv[node], re = rs_cv[node + 1];
        float s = 0.f, a = 0.f;
        for (int e = rs + tid; e < re; e += 256) {
            int si = csr_cv[e];
            float w = __expf(qs * ko[si]);
            s += w;
            a = fmaf(w, vo[si], a);
        }
        #pragma unroll
        for (int off = 32; off >= 1; off >>= 1) {
            s += __shfl_xor(s, off, 64);
            a += __shfl_xor(a, off, 64);
        }
        int lane = tid & 63, wid = tid >> 6;
        if (lane == 0) { sms[wid] = s; sma[wid] = a; }
        __syncthreads();
        if (tid == 0) {
            float S = sms[0] + sms[1] + sms[2] + sms[3];
            float A_ = sma[0] + sma[1] + sma[2] + sma[3];
            float agg = (S > 0.f) ? A_ / S : 0.f;
            agg *= mrel_o[0];
            outl[node] = gelu_tanh(agg) * Wa_o[0] + ba_o[0];
        }
        return;
    }

    int row0 = blockIdx.x * 64;
    int tx = tid & 15;   // cols tx*4..+3 and 64+tx*4..+3
    int ty = tid >> 4;   // rows ty*4..+3
    #pragma unroll
    for (int i = 0; i < 8; i++) {
        int slot = tid + i * 256;            // [0,2048) float4 slots
        int r = slot >> 5, kq = slot & 31;
        int rr = row0 + r;
        float4 v = make_float4(0.f, 0.f, 0.f, 0.f);
        if (rr < M) v = *(const float4*)(A + (size_t)rr * lda + kq * 4);
        *(float4*)&As[r][kq * 4] = v;
    }
    const float* Ws[3] = {W0, W1, W2};
    const float* bs[3] = {b0, b1, b2};
    for (int jw = 0; jw < 3; jw++) {
        float acc[4][8] = {};
        for (int k0 = 0; k0 < 128; k0 += 32) {
            __syncthreads();
            #pragma unroll
            for (int i = 0; i < 4; i++) {
                int slot = tid + i * 256;    // [0,1024)
                int kr = slot >> 5, cq = slot & 31;
                *(float4*)&Bs[kr][cq * 4] = *(const float4*)(Ws[jw] + (size_t)(k0 + kr) * 128 + cq * 4);
            }
            __syncthreads();
            #pragma unroll
            for (int k4 = 0; k4 < 32; k4 += 4) {
                float4 av[4];
                #pragma unroll
                for (int i = 0; i < 4; i++)
                    av[i] = *(const float4*)&As[ty * 4 + i][k0 + k4];
                #pragma unroll
                for (int kk = 0; kk < 4; kk++) {
                    float4 bl = *(const float4*)&Bs[k4 + kk][tx * 4];
                    float4 bh = *(const float4*)&Bs[k4 + kk][64 + tx * 4];
                    float bb[8] = {bl.x, bl.y, bl.z, bl.w, bh.x, bh.y, bh.z, bh.w};
                    #pragma unroll
                    for (int i = 0; i < 4; i++) {
                        float a = ((const float*)&av[i])[kk];
                        #pragma unroll
                        for (int j = 0; j < 8; j++)
                            acc[i][j] = fmaf(a, bb[j], acc[i][j]);
                    }
                }
            }
        }
        #pragma unroll
        for (int i = 0; i < 4; i++) {
            int r = row0 + ty * 4 + i;
            if (r >= M) continue;
            float vals[8];
            #pragma unroll
            for (int j = 0; j < 4; j++) {
                vals[j]     = acc[i][j]     + bs[jw][tx * 4 + j];
                vals[4 + j] = acc[i][4 + j] + bs[jw][64 + tx * 4 + j];
            }
            if (jw == 0) {
                float* op = out + (size_t)r * 256;
                *(float4*)(op + tx * 4)      = make_float4(vals[0], vals[1], vals[2], vals[3]);
                *(float4*)(op + 64 + tx * 4) = make_float4(vals[4], vals[5], vals[6], vals[7]);
            } else {
                __half* hp = (__half*)((char*)out + ((size_t)r << 10) + 512 + (jw - 1) * 256);
                __half2 ha = __float22half2_rn(make_float2(vals[0], vals[1]));
                __half2 hb = __float22half2_rn(make_float2(vals[2], vals[3]));
                __half2 hc = __float22half2_rn(make_float2(vals[4], vals[5]));
                __half2 hd = __float22half2_rn(make_float2(vals[6], vals[7]));
                uint2 wlo, whi;
                wlo.x = *(unsigned*)&ha; wlo.y = *(unsigned*)&hb;
                whi.x = *(unsigned*)&hc; whi.y = *(unsigned*)&hd;
                *(uint2*)(hp + tx * 4)      = wlo;
                *(uint2*)(hp + 64 + tx * 4) = whi;
            }
        }
    }
}

// ---------------- fp32 GEMM, split cols, + fused scalar projections ------------
// Merged dual dispatch: blocks [0,nblk1) run GEMM-1 (c-side), blocks >= nblk1
// run GEMM-2 (v-side). All parameter selection is wave-uniform.
__global__ __launch_bounds__(256) void gemm128(
    int nblk1,
    // primary (c-side)
    const float* __restrict__ A1, int lda1, const float* __restrict__ W1,
    const float* __restrict__ bias1, float* __restrict__ out1, int M1,
    const float* __restrict__ gate1, const float* __restrict__ xold1,
    const float* __restrict__ wk1, const float* __restrict__ bk1, float* __restrict__ ko1,
    const float* __restrict__ wv1, const float* __restrict__ bv1, float* __restrict__ vo1,
    // secondary (v-side)
    const float* __restrict__ A2, int lda2, const float* __restrict__ W2,
    const float* __restrict__ bias2, float* __restrict__ out2, int M2,
    const float* __restrict__ gate2, const float* __restrict__ xold2,
    const float* __restrict__ wk2, const float* __restrict__ bk2, float* __restrict__ ko2)
{
    __shared__ float As[64][36];    // 9 KB (32-wide k-tile, +4 pad)
    __shared__ float Bs[32][128];   // 16 KB
    bool sec = (blockIdx.x >= (unsigned)nblk1);
    const float* A    = sec ? A2 : A1;
    int lda           = sec ? lda2 : lda1;
    const float* W    = sec ? W2 : W1;
    const float* bias = sec ? bias2 : bias1;
    float* out        = sec ? out2 : out1;
    int M             = sec ? M2 : M1;
    const float* gate = sec ? gate2 : gate1;
    const float* xold = sec ? xold2 : xold1;
    const float* wk_o = sec ? wk2 : wk1;
    const float* bk_o = sec ? bk2 : bk1;
    float* ko         = sec ? ko2 : ko1;
    const float* wv_o = sec ? nullptr : wv1;
    const float* bv_o = sec ? nullptr : bv1;
    float* vo         = sec ? nullptr : vo1;

    int tid = threadIdx.x;
    int row0 = (sec ? (blockIdx.x - nblk1) : blockIdx.x) * 64;
    int tx = tid & 15;
    int ty = tid >> 4;
    float acc[4][8] = {};
    for (int k0 = 0; k0 < 128; k0 += 32) {
        __syncthreads();
        #pragma unroll
        for (int i = 0; i < 2; i++) {
            int slot = tid + i * 256;            // [0,512) float4 slots
            int r = slot >> 3, kq = slot & 7;
            int rr = row0 + r;
            float4 v = make_float4(0.f, 0.f, 0.f, 0.f);
            if (rr < M) v = *(const float4*)(A + (size_t)rr * lda + k0 + kq * 4);
            *(float4*)&As[r][kq * 4] = v;
        }
        #pragma unroll
        for (int i = 0; i < 4; i++) {
            int slot = tid + i * 256;            // [0,1024)
            int kr = slot >> 5, cq = slot & 31;
            *(float4*)&Bs[kr][cq * 4] = *(const float4*)(W + (size_t)(k0 + kr) * 128 + cq * 4);
        }
        __syncthreads();
        #pragma unroll
        for (int k4 = 0; k4 < 32; k4 += 4) {
            float4 av[4];
            #pragma unroll
            for (int i = 0; i < 4; i++)
                av[i] = *(const float4*)&As[ty * 4 + i][k4];
            #pragma unroll
            for (int kk = 0; kk < 4; kk++) {
                float4 bl = *(const float4*)&Bs[k4 + kk][tx * 4];
                float4 bh = *(const float4*)&Bs[k4 + kk][64 + tx * 4];
                float bb[8] = {bl.x, bl.y, bl.z, bl.w, bh.x, bh.y, bh.z, bh.w};
                #pragma unroll
                for (int i = 0; i < 4; i++) {
                    float a = ((const float*)&av[i])[kk];
                    #pragma unroll
                    for (int j = 0; j < 8; j++)
                        acc[i][j] = fmaf(a, bb[j], acc[i][j]);
                }
            }
        }
    }
    float g = 1.f, og = 0.f;
    if (gate != nullptr) { g = 1.f / (1.f + expf(-gate[0])); og = 1.f - g; }
    float wkr[8], wvr[8];
    if (wk_o != nullptr) {
        #pragma unroll
        for (int j = 0; j < 4; j++) {
            wkr[j]     = wk_o[tx * 4 + j];
            wkr[4 + j] = wk_o[64 + tx * 4 + j];
        }
    }
    if (wv_o != nullptr) {
        #pragma unroll
        for (int j = 0; j < 4; j++) {
            wvr[j]     = wv_o[tx * 4 + j];
            wvr[4 + j] = wv_o[64 + tx * 4 + j];
        }
    }
    #pragma unroll
    for (int i = 0; i < 4; i++) {
        int r = row0 + ty * 4 + i;
        if (r >= M) continue;   // uniform across each 16-lane group
        float vals[8];
        #pragma unroll
        for (int j = 0; j < 4; j++) {
            float v0 = acc[i][j]     + bias[tx * 4 + j];
            float v1 = acc[i][4 + j] + bias[64 + tx * 4 + j];
            if (gate != nullptr) {
                v0 = g * v0 + og * xold[(size_t)r * 128 + tx * 4 + j];
                v1 = g * v1 + og * xold[(size_t)r * 128 + 64 + tx * 4 + j];
            }
            vals[j] = v0;
            vals[4 + j] = v1;
        }
        float* op = out + (size_t)r * 128;
        *(float4*)(op + tx * 4)      = make_float4(vals[0], vals[1], vals[2], vals[3]);
        *(float4*)(op + 64 + tx * 4) = make_float4(vals[4], vals[5], vals[6], vals[7]);
        if (wk_o != nullptr) {
            float pk = 0.f, pv = 0.f;
            #pragma unroll
            for (int j = 0; j < 8; j++) pk = fmaf(vals[j], wkr[j], pk);
            if (wv_o != nullptr) {
                #pragma unroll
                for (int j = 0; j < 8; j++) pv = fmaf(vals[j], wvr[j], pv);
            }
            #pragma unroll
            for (int off = 1; off < 16; off <<= 1) {
                pk += __shfl_xor(pk, off, 64);
                if (wv_o != nullptr) pv += __shfl_xor(pv, off, 64);
            }
            if (tx == 0) {
                ko[r] = pk + bk_o[0];
                if (wv_o != nullptr) vo[r] = pv + bv_o[0];
            }
        }
    }
}

// ---------------- pipelined fp16-payload edge accumulation --------------------
// Per 64-edge chunk: one wave-coalesced csr load, indices via shfl; each edge's
// k+v is 512 B contiguous fp16 (half the fp32 traffic). Register-double-buffered
// 2-round pipeline; clamped tail loads masked via w=0. All math fp32.
__device__ __forceinline__ void gather_pipe(
    const float* __restrict__ xqkv, const int* __restrict__ csr,
    int e0, int e1, int g, int j, const float* q8,
    float& s_io, float acc[8])
{
    int lane = threadIdx.x & 63;
    float s = s_io;
    const char* base = (const char*)xqkv;
    for (int cs = e0; cs < e1; cs += 64) {
        int n = e1 - cs; if (n > 64) n = 64;
        int nm1 = n - 1;
        int idx0 = 0;
        if (lane < n) idx0 = csr[cs + lane];
        int R = (n + 7) >> 3;   // rounds of 8 edges (2 per group)

        uint4 ak0, av0, ak1, av1;   // buffer A (even rounds, 2 edges)
        uint4 bk0, bv0, bk1, bv1;   // buffer B (odd rounds)

#define LD2(E0_, E1_, K0, V0, K1, V1) { \
            int i0_ = __shfl(idx0, min((E0_), nm1), 64); \
            int i1_ = __shfl(idx0, min((E1_), nm1), 64); \
            const uint4* p0_ = (const uint4*)(base + ((size_t)i0_ << 10) + 512 + 16 * j); \
            const uint4* p1_ = (const uint4*)(base + ((size_t)i1_ << 10) + 512 + 16 * j); \
            K0 = p0_[0]; V0 = p0_[16]; \
            K1 = p1_[0]; V1 = p1_[16]; }

#define CMP(E0_, E1_, K0, V0, K1, V1) { \
            float k0f[8], k1f[8], v0f[8], v1f[8]; \
            h8_to_f8(K0, k0f); h8_to_f8(K1, k1f); \
            float d0_ = dot8f(q8, k0f); \
            float d1_ = dot8f(q8, k1f); \
            d0_ += __shfl_xor(d0_, 1, 64); d1_ += __shfl_xor(d1_, 1, 64); \
            d0_ += __shfl_xor(d0_, 2, 64); d1_ += __shfl_xor(d1_, 2, 64); \
            float w0_ = ((E0_) < n) ? __expf(d0_) : 0.f; \
            float w1_ = ((E1_) < n) ? __expf(d1_) : 0.f; \
            s += w0_ + w1_; \
            h8_to_f8(V0, v0f); h8_to_f8(V1, v1f); \
            acc[0] = fmaf(w0_, v0f[0], acc[0]); acc[0] = fmaf(w1_, v1f[0], acc[0]); \
            acc[1] = fmaf(w0_, v0f[1], acc[1]); acc[1] = fmaf(w1_, v1f[1], acc[1]); \
            acc[2] = fmaf(w0_, v0f[2], acc[2]); acc[2] = fmaf(w1_, v1f[2], acc[2]); \
            acc[3] = fmaf(w0_, v0f[3], acc[3]); acc[3] = fmaf(w1_, v1f[3], acc[3]); \
            acc[4] = fmaf(w0_, v0f[4], acc[4]); acc[4] = fmaf(w1_, v1f[4], acc[4]); \
            acc[5] = fmaf(w0_, v0f[5], acc[5]); acc[5] = fmaf(w1_, v1f[5], acc[5]); \
            acc[6] = fmaf(w0_, v0f[6], acc[6]); acc[6] = fmaf(w1_, v1f[6], acc[6]); \
            acc[7] = fmaf(w0_, v0f[7], acc[7]); acc[7] = fmaf(w1_, v1f[7], acc[7]); }

        // prefetch round 0 (A) and round 1 (B)
        LD2(g, g + 4, ak0, av0, ak1, av1);
        if (R > 1) LD2(g + 8, g + 12, bk0, bv0, bk1, bv1);

        for (int r = 0; r < R; r += 2) {
            int er = g + 8 * r;
            CMP(er, er + 4, ak0, av0, ak1, av1);
            if (r + 2 < R) {
                int ep = g + 8 * (r + 2);
                LD2(ep, ep + 4, ak0, av0, ak1, av1);
            }
            if (r + 1 < R) {
                int eo = g + 8 * (r + 1);
                CMP(eo, eo + 4, bk0, bv0, bk1, bv1);
                if (r + 3 < R) {
                    int eq = g + 8 * (r + 3);
                    LD2(eq, eq + 4, bk0, bv0, bk1, bv1);
                }
            }
        }
#undef LD2
#undef CMP
    }
    s_io = s;
}

// ---------------- unified attention: cv blocks [0,256) + cc blocks -------------
__global__ __launch_bounds__(256) void attn_uni(
    float* xqkv,
    const float* __restrict__ xv, const float* __restrict__ wqt,
    const float* __restrict__ bqt,
    const int* __restrict__ rs_cc, const int* __restrict__ csr_cc,
    const int* __restrict__ rs_cv, const int* __restrict__ csr_cv,
    const float* __restrict__ mrel_cc, const float* __restrict__ mrel_cv,
    float* __restrict__ aggv, int n_c)
{
    __shared__ float smem[800];   // 3.2 KB, carved per role
    int lane = threadIdx.x & 63, wid = threadIdx.x >> 6;
    int g = lane >> 4, j = lane & 15;

    if (blockIdx.x < N_V) {
        // ---------------- cv node ----------------
        int node = blockIdx.x;
        float* qrow = smem;          // [128]
        float* sm_s = smem + 128;    // [4][4]
        float* sm_a = smem + 144;    // [4][128]
        float* orow = smem + 656;    // [144]
        if (wid < 2) {
            int col = wid * 64 + lane;
            float a = bqt[col];
            const float* xr = xv + (size_t)node * 128;
            for (int k = 0; k < 128; k++)
                a = fmaf(xr[k], wqt[(size_t)k * 128 + col], a);
            qrow[col] = a;
        }
        __syncthreads();
        float q8[8];
        *(float4*)&q8[0] = *(const float4*)&qrow[8 * j];
        *(float4*)&q8[4] = *(const float4*)&qrow[8 * j + 4];
        int rs = rs_cv[node], re = rs_cv[node + 1];
        int cnt = re - rs;
        int per = (cnt + 3) >> 2;
        int e0 = rs + wid * per, e1 = min(e0 + per, re);
        float s = 0.f;
        float acc[8] = {};
        gather_pipe(xqkv, csr_cv, e0, e1, g, j, q8, s, acc);
        #pragma unroll
        for (int i = 0; i < 8; i++) {
            acc[i] += __shfl_xor(acc[i], 16, 64);
            acc[i] += __shfl_xor(acc[i], 32, 64);
        }
        s += __shfl_xor(s, 16, 64);
        s += __shfl_xor(s, 32, 64);
        if (g == 0) {
            *(float4*)&sm_a[wid * 128 + 8 * j]     = make_float4(acc[0], acc[1], acc[2], acc[3]);
            *(float4*)&sm_a[wid * 128 + 8 * j + 4] = make_float4(acc[4], acc[5], acc[6], acc[7]);
            if ((j & 3) == 0) sm_s[wid * 4 + (j >> 2)] = s;
        }
        __syncthreads();
        if (threadIdx.x < 64) {
            int lp = 2 * lane;
            int h = lp >> 5;
            float S = 0.f, AX = 0.f, AY = 0.f;
            #pragma unroll
            for (int i = 0; i < 4; i++) {
                S  += sm_s[i * 4 + h];
                float2 a2 = *(const float2*)&sm_a[i * 128 + lp];
                AX += a2.x;
                AY += a2.y;
            }
            float inv = (S > 0.f) ? 1.f / S : 0.f;
            int off = lp + 4 * h;   // padded
            orow[off]     = AX * inv;
            orow[off + 1] = AY * inv;
            int eo = lp & 31;
            const float* mr = mrel_cv + h * 1024 + eo;
            const float* rb = orow + 36 * h;
            float t0 = 0.f, t1 = 0.f;
            #pragma unroll
            for (int d = 0; d < 32; d++) {
                float a = rb[d];
                t0 = fmaf(a, mr[d * 32], t0);
                t1 = fmaf(a, mr[d * 32 + 1], t1);
            }
            aggv[(size_t)node * 128 + lp]     = gelu_tanh(t0);
            aggv[(size_t)node * 128 + lp + 1] = gelu_tanh(t1);
        }
    } else {
        // ---------------- cc nodes (4 per block, 1 wave each) ----------------
        float* rowbuf = smem;        // [4][144]
        int node = (blockIdx.x - N_V) * 4 + wid;
        if (node >= n_c) return;
        const float* qp = xqkv + (size_t)node * 256 + 8 * j;
        float q8[8];
        *(float4*)&q8[0] = *(const float4*)qp;
        *(float4*)&q8[4] = *(const float4*)(qp + 4);
        int rs = rs_cc[node], re = rs_cc[node + 1];
        float s = 0.f;
        float acc[8] = {};
        gather_pipe(xqkv, csr_cc, rs, re, g, j, q8, s, acc);
        #pragma unroll
        for (int i = 0; i < 8; i++) {
            acc[i] += __shfl_xor(acc[i], 16, 64);
            acc[i] += __shfl_xor(acc[i], 32, 64);
        }
        s += __shfl_xor(s, 16, 64);
        s += __shfl_xor(s, 32, 64);
        float inv = (s > 0.f) ? 1.f / s : 0.f;
        float* rb_w = rowbuf + wid * 144;
        if (g == 0) {
            int off = 8 * j + 4 * (j >> 2);   // +4 pad per head
            float4 o0 = make_float4(acc[0] * inv, acc[1] * inv, acc[2] * inv, acc[3] * inv);
            float4 o1 = make_float4(acc[4] * inv, acc[5] * inv, acc[6] * inv, acc[7] * inv);
            *(float4*)&rb_w[off]     = o0;
            *(float4*)&rb_w[off + 4] = o1;
        }
        // intra-wave DS ordering: no barrier needed
        int lp = 2 * lane;
        int h = lp >> 5, eo = lp & 31;
        const float* mr = mrel_cc + h * 1024 + eo;
        const float* rb = rb_w + 36 * h;
        float t0 = 0.f, t1 = 0.f;
        #pragma unroll
        for (int d = 0; d < 32; d++) {
            float a = rb[d];
            t0 = fmaf(a, mr[d * 32], t0);
            t1 = fmaf(a, mr[d * 32 + 1], t1);
        }
        float2 o = make_float2(gelu_tanh(t0), gelu_tanh(t1));
        *(float2*)(xqkv + (size_t)node * 256 + lp) = o;
    }
}

// ---------------- out-conv scalar attention (standalone, last layer) -----------
__global__ __launch_bounds__(256) void attn_out(
    const float* __restrict__ qo, const float* __restrict__ ko, const float* __restrict__ vo,
    const int* __restrict__ rowstart, const int* __restrict__ csr,
    const float* __restrict__ arel_o, const float* __restrict__ prel_o,
    const float* __restrict__ mrel_o, const float* __restrict__ Wa_o,
    const float* __restrict__ ba_o, float* __restrict__ outl)
{
    int node = blockIdx.x;
    float qs = qo[node] * arel_o[0] * prel_o[0];
    int rs = rowstart[node], re = rowstart[node + 1];
    float s = 0.f, a = 0.f;
    for (int e = rs + (int)threadIdx.x; e < re; e += 256) {
        int si = csr[e];
        float w = __expf(qs * ko[si]);
        s += w;
        a = fmaf(w, vo[si], a);
    }
    #pragma unroll
    for (int off = 32; off >= 1; off >>= 1) {
        s += __shfl_xor(s, off, 64);
        a += __shfl_xor(a, off, 64);
    }
    __shared__ float sms[4], sma[4];
    int lane = threadIdx.x & 63, wid = threadIdx.x >> 6;
    if (lane == 0) { sms[wid] = s; sma[wid] = a; }
    __syncthreads();
    if (threadIdx.x == 0) {
        float S = sms[0] + sms[1] + sms[2] + sms[3];
        float A = sma[0] + sma[1] + sma[2] + sma[3];
        float agg = (S > 0.f) ? A / S : 0.f;
        agg *= mrel_o[0];
        outl[node] = gelu_tanh(agg) * Wa_o[0] + ba_o[0];
    }
}

// ---------------- final head: JK-max -> node_fc -> MLP ------------------------
__global__ void final_head(const float* __restrict__ outs,
    const float* __restrict__ fc_W, const float* __restrict__ fc_b,
    const float* __restrict__ W1, const float* __restrict__ b1,
    const float* __restrict__ W2, const float* __restrict__ b2,
    float* __restrict__ out)
{
    int b = threadIdx.x;
    if (b >= 64) return;
    float h = fc_b[0];
    #pragma unroll
    for (int v = 0; v < 4; v++) {
        int n = b * 4 + v;
        float jk = fmaxf(fmaxf(outs[0 * N_V + n], outs[1 * N_V + n]), outs[2 * N_V + n]);
        h = fmaf(jk, fc_W[v], h);
    }
    h = gelu_tanh(h);
    float h0 = gelu_tanh(h * W1[0] + b1[0]);
    float h1 = gelu_tanh(h * W1[1] + b1[1]);
    out[b] = h0 * W2[0] + h1 * W2[1] + b2[0];
}

// ---------------- orchestration ----------------------------------------------
extern "C" void kernel_launch(void* const* d_in, const int* in_sizes, int n_in,
                              void* d_out, int out_size, void* d_ws, size_t ws_size,
                              hipStream_t stream) {
    (void)in_sizes; (void)n_in; (void)out_size; (void)ws_size;
    const float* x_cell  = (const float*)d_in[0];
    const float* x_vcell = (const float*)d_in[1];
    const float* Wk   = (const float*)d_in[2];
    const float* bk   = (const float*)d_in[3];
    const float* Wq   = (const float*)d_in[4];
    const float* bq   = (const float*)d_in[5];
    const float* Wv   = (const float*)d_in[6];
    const float* bv   = (const float*)d_in[7];
    const float* Wa   = (const float*)d_in[8];
    const float* ba   = (const float*)d_in[9];
    const float* skip = (const float*)d_in[10];
    const float* arel = (const float*)d_in[11];
    const float* mrel = (const float*)d_in[12];
    const float* prel = (const float*)d_in[13];
    const float* Wk_o = (const float*)d_in[14];
    const float* bk_o = (const float*)d_in[15];
    const float* Wq_o = (const float*)d_in[16];
    const float* bq_o = (const float*)d_in[17];
    const float* Wv_o = (const float*)d_in[18];
    const float* bv_o = (const float*)d_in[19];
    const float* Wa_o = (const float*)d_in[20];
    const float* ba_o = (const float*)d_in[21];
    const float* arel_o = (const float*)d_in[22];
    const float* mrel_o = (const float*)d_in[23];
    const float* prel_o = (const float*)d_in[24];
    const float* fc_W  = (const float*)d_in[25];
    const float* fc_b  = (const float*)d_in[26];
    const float* mlp_W1 = (const float*)d_in[27];
    const float* mlp_b1 = (const float*)d_in[28];
    const float* mlp_W2 = (const float*)d_in[29];
    const float* mlp_b2 = (const float*)d_in[30];
    const int* src_cc = (const int*)d_in[31];
    const int* dst_cc = (const int*)d_in[32];
    const int* src_cv = (const int*)d_in[33];
    const int* dst_cv = (const int*)d_in[34];

    // workspace carve-up (256B aligned)
    char* p = (char*)d_ws;
    auto alloc = [&](size_t bytes) -> char* {
        uintptr_t q = ((uintptr_t)p + 255) & ~(uintptr_t)255;
        p = (char*)(q + bytes);
        return (char*)q;
    };
    float* WQT  = (float*)alloc(sizeof(float) * NL * 2 * CH * CH);
    float* BQT  = (float*)alloc(sizeof(float) * NL * 2 * CH);
    float* XC   = (float*)alloc(sizeof(float) * (size_t)N_C * CH);
    float* XV   = (float*)alloc(sizeof(float) * (size_t)N_V * CH);
    float* XQKV = (float*)alloc(sizeof(float) * (size_t)N_C * 256);  // [q~ f32 | k,v fp16]
    float* AGGV = (float*)alloc(sizeof(float) * (size_t)N_V * CH);
    float* KO   = (float*)alloc(sizeof(float) * N_C);
    float* VO   = (float*)alloc(sizeof(float) * N_C);
    float* QO   = (float*)alloc(sizeof(float) * N_V);
    float* OUTS = (float*)alloc(sizeof(float) * NL * N_V);
    // CSR-build scratch (hist region zeroed in one memset)
    int* bhist    = (int*)alloc(sizeof(int) * 512);
    int* bhist_cc = bhist;
    int* bhist_cv = bhist + 256;
    int* bbase_cc = (int*)alloc(sizeof(int) * 257);
    int* cur_cc   = (int*)alloc(sizeof(int) * 256);
    int* cur_cv   = (int*)alloc(sizeof(int) * 256);
    int* rs_cc    = (int*)alloc(sizeof(int) * (N_C + 1));
    int* rs_cv    = (int*)alloc(sizeof(int) * (N_V + 1));
    int* csr_cc   = (int*)alloc(sizeof(int) * NE1);
    int* csr_cv   = (int*)alloc(sizeof(int) * NE2);
    int2* tmp_cc  = (int2*)alloc(sizeof(int2) * NE1);

    // ---- setup: composed weights + CSR (two-level counting sort) ----
    compose_wq<<<CDIV(NL * 2 * (CH + 1) * CH, 256), 256, 0, stream>>>(
        Wq, bq, arel, prel, WQT, BQT);
    hipMemsetAsync(bhist, 0, sizeof(int) * 512, stream);
    bucket_hist<<<CDIV(NE1, EPB), 256, 0, stream>>>(dst_cc, NE1, 8, bhist_cc);
    bucket_hist<<<CDIV(NE2, EPB), 256, 0, stream>>>(dst_cv, NE2, 0, bhist_cv);
    scan256<<<1, 256, 0, stream>>>(bhist_cc, bbase_cc, cur_cc);
    scan256<<<1, 256, 0, stream>>>(bhist_cv, rs_cv, cur_cv);   // rs_cv IS the cv row starts
    partition_edges<true ><<<CDIV(NE1, EPB), 256, 0, stream>>>(src_cc, dst_cc, NE1, 8,
                                                               cur_cc, tmp_cc, nullptr);
    partition_edges<false><<<CDIV(NE2, EPB), 256, 0, stream>>>(src_cv, dst_cv, NE2, 0,
                                                               cur_cv, nullptr, csr_cv);
    bucket_finalize<<<CDIV(N_C, 256), 256, 0, stream>>>(tmp_cc, bbase_cc, N_C, NE1,
                                                        rs_cc, csr_cc);

    const int gb_c = CDIV(N_C, 64);             // 938
    const int gb_v = CDIV(N_V, 64);             // 4
    const int gb_attn = N_V + CDIV(N_C, 4);     // 256 cv + 15000 cc blocks

    for (int li = 0; li < NL; li++) {
        const float* xc_src = (li == 0) ? x_cell : XC;
        const float* xv_src = (li == 0) ? x_vcell : XV;
        size_t w0 = (size_t)(li * 2) * CH * CH;
        size_t w1 = (size_t)(li * 2 + 1) * CH * CH;
        int b0 = (li * 2) * CH, b1 = (li * 2 + 1) * CH;

        // fused q~/k/v GEMM; layers >0 append prev-layer out-conv attention tail
        int tail = (li > 0) ? N_V : 0;
        gemm_qkv<<<gb_c + tail, 256, 0, stream>>>(
            gb_c, xc_src, 128, N_C,
            WQT + w0, Wk + w0, Wv + w0,
            BQT + b0, bk + b0, bv + b0, XQKV,
            QO, KO, VO, rs_cv, csr_cv,
            arel_o + (li - 1), prel_o + (li - 1), mrel_o + (li - 1),
            Wa_o + (li - 1), ba_o + (li - 1),
            (li > 0) ? (OUTS + (li - 1) * N_V) : nullptr);

        // unified attention: cv (inline q~v projection, 4 waves/node) + cc
        attn_uni<<<gb_attn, 256, 0, stream>>>(
            XQKV, xv_src, WQT + w1, BQT + b1,
            rs_cc, csr_cc, rs_cv, csr_cv,
            mrel + (size_t)(li * 2) * NH * HD * HD,
            mrel + (size_t)(li * 2 + 1) * NH * HD * HD,
            AGGV, N_C);

        // merged Wa GEMMs (c-side + v-side in one dispatch) with skip epilogue;
        // c-side fuses out-conv k/v projections, v-side fuses q projection
        gemm128<<<gb_c + gb_v, 256, 0, stream>>>(
            gb_c,
            XQKV, 256, Wa + w0, ba + b0, XC, N_C,
            skip + li * 2, xc_src,
            Wk_o + li * CH, bk_o + li, KO,
            Wv_o + li * CH, bv_o + li, VO,
            AGGV, 128, Wa + w1, ba + b1, XV, N_V,
            skip + li * 2 + 1, xv_src,
            Wq_o + li * CH, bq_o + li, QO);
    }

    // last layer's out-conv attention, then final head
    attn_out<<<N_V, 256, 0, stream>>>(QO, KO, VO, rs_cv, csr_cv,
                                      arel_o + (NL - 1), prel_o + (NL - 1), mrel_o + (NL - 1),
                                      Wa_o + (NL - 1), ba_o + (NL - 1), OUTS + (NL - 1) * N_V);
    final_head<<<1, 64, 0, stream>>>(OUTS, fc_W, fc_b, mlp_W1, mlp_b1, mlp_W2, mlp_b2,
                                     (float*)d_out);
}

// Round 3
// 835.510 us; speedup vs baseline: 1.2208x; 1.0807x over previous
//
#include <hip/hip_runtime.h>
#include <hip/hip_fp16.h>
#include <math.h>
#include <stdint.h>

#define N_C 60000
#define N_V 256
#define CH 128
#define NH 4
#define HD 32
#define NL 3
#define NE1 600000
#define NE2 240000

#define CDIV(a,b) (((a)+(b)-1)/(b))
#define EPB 1024   // elems per block in counting-sort kernels

// XQKV record layout (per node, 1024 B stride = 256 floats):
//   bytes [0,512)    : q~ (layer in) / agg (layer out)  f32 x128
//   bytes [512,768)  : k   fp16 x128
//   bytes [768,1024) : v   fp16 x128

typedef _Float16 f16x8 __attribute__((ext_vector_type(8)));
typedef _Float16 f16x4 __attribute__((ext_vector_type(4)));
typedef float f32x4 __attribute__((ext_vector_type(4)));

__device__ __forceinline__ float gelu_tanh(float x) {
    float x3 = x * x * x;
    float t = tanhf(0.7978845608028654f * (x + 0.044715f * x3));
    return 0.5f * x * (1.0f + t);
}

__device__ __forceinline__ void h8_to_f8(uint4 w, float* f) {
    float2 a = __half22float2(*(const __half2*)&w.x);
    float2 b = __half22float2(*(const __half2*)&w.y);
    float2 c = __half22float2(*(const __half2*)&w.z);
    float2 d = __half22float2(*(const __half2*)&w.w);
    f[0] = a.x; f[1] = a.y; f[2] = b.x; f[3] = b.y;
    f[4] = c.x; f[5] = c.y; f[6] = d.x; f[7] = d.y;
}

__device__ __forceinline__ float dot8f(const float* q, const float* k) {
    float d = q[0] * k[0];
    d = fmaf(q[1], k[1], d);
    d = fmaf(q[2], k[2], d);
    d = fmaf(q[3], k[3], d);
    d = fmaf(q[4], k[4], d);
    d = fmaf(q[5], k[5], d);
    d = fmaf(q[6], k[6], d);
    d = fmaf(q[7], k[7], d);
    return d;
}

// ---------------- weight composition: W~q = Wq . arel  (prel/sqrt(D) folded) ---
__global__ __launch_bounds__(256) void compose_wq(
    const float* __restrict__ Wq, const float* __restrict__ bq,
    const float* __restrict__ arel, const float* __restrict__ prel,
    float* __restrict__ WQT, float* __restrict__ BQT)
{
    int gid = blockIdx.x * blockDim.x + threadIdx.x;
    const int total = NL * 2 * (CH + 1) * CH;
    if (gid >= total) return;
    int li2 = gid / ((CH + 1) * CH);
    int rem = gid % ((CH + 1) * CH);
    int c   = rem / CH;          // 0..CH ; CH => bias row
    int col = rem % CH;
    int h = col >> 5, d = col & 31;
    const float* ar = arel + (li2 * NH + h) * (HD * HD) + d * HD;  // [e]
    float scale = prel[li2 * NH + h] * 0.17677669529663687f;       // prel/sqrt(32)
    const float* src = (c < CH) ? (Wq + ((size_t)li2 * CH + c) * CH + h * HD)
                                : (bq + li2 * CH + h * HD);
    float acc = 0.f;
    #pragma unroll
    for (int e = 0; e < HD; e++) acc = fmaf(src[e], ar[e], acc);
    acc *= scale;
    if (c < CH) WQT[((size_t)li2 * CH + c) * CH + col] = acc;
    else        BQT[li2 * CH + col] = acc;
}

// ---------------- weight fp16 transpose: WT16[b][n][k] = W[k][n] --------------
// b = li*4 + w ; w: 0=WQT(c-side) 1=Wk 2=Wv 3=Wa(c-side)
__global__ __launch_bounds__(128) void cvt_w16(
    const float* __restrict__ WQT, const float* __restrict__ Wk,
    const float* __restrict__ Wv, const float* __restrict__ Wa,
    _Float16* __restrict__ WT16)
{
    int b = blockIdx.x;
    int li = b >> 2, w = b & 3;
    size_t off = (size_t)(li * 2) * CH * CH;
    const float* src = (w == 0) ? (WQT + off)
                     : (w == 1) ? (Wk + off)
                     : (w == 2) ? (Wv + off)
                                : (Wa + off);
    _Float16* dst = WT16 + (size_t)b * CH * CH;
    int n = threadIdx.x;
    for (int k = 0; k < CH; k++)
        dst[n * CH + k] = (_Float16)src[k * CH + n];
}

// ================= CSR build: two-level LDS counting sort =====================
__global__ __launch_bounds__(256) void bucket_hist(const int* __restrict__ dst, int E,
                                                   int shift, int* __restrict__ bhist)
{
    __shared__ int h[256];
    int t = threadIdx.x;
    h[t] = 0;
    __syncthreads();
    int i0 = blockIdx.x * EPB, i1 = min(i0 + EPB, E);
    for (int i = i0 + t; i < i1; i += 256)
        atomicAdd(&h[(dst[i] >> shift) & 255], 1);
    __syncthreads();
    if (h[t] > 0) atomicAdd(&bhist[t], h[t]);
}

__global__ __launch_bounds__(256) void scan256(const int* __restrict__ h,
                                               int* __restrict__ base, int* __restrict__ cur)
{
    __shared__ int p[256];
    int t = threadIdx.x;
    int v = h[t];
    p[t] = v;
    __syncthreads();
    for (int off = 1; off < 256; off <<= 1) {
        int u = (t >= off) ? p[t - off] : 0;
        __syncthreads();
        p[t] += u;
        __syncthreads();
    }
    base[t] = p[t] - v;
    cur[t]  = p[t] - v;
    if (t == 255) base[256] = p[255];
}

template<bool PAIR>
__global__ __launch_bounds__(256) void partition_edges(
    const int* __restrict__ src, const int* __restrict__ dst, int E, int shift,
    int* __restrict__ cur, int2* __restrict__ tmp_pair, int* __restrict__ out_src)
{
    __shared__ int cnt[256], base[256], cnt2[256];
    int t = threadIdx.x;
    cnt[t] = 0; cnt2[t] = 0;
    __syncthreads();
    int i0 = blockIdx.x * EPB, i1 = min(i0 + EPB, E);
    for (int i = i0 + t; i < i1; i += 256)
        atomicAdd(&cnt[(dst[i] >> shift) & 255], 1);
    __syncthreads();
    if (cnt[t] > 0) base[t] = atomicAdd(&cur[t], cnt[t]);
    __syncthreads();
    for (int i = i0 + t; i < i1; i += 256) {
        int d = dst[i];
        int dig = (d >> shift) & 255;
        int r = atomicAdd(&cnt2[dig], 1);
        int pos = base[dig] + r;
        if constexpr (PAIR) tmp_pair[pos] = make_int2(src[i], d);
        else                out_src[pos] = src[i];
    }
}

__global__ __launch_bounds__(256) void bucket_finalize(
    const int2* __restrict__ tmp, const int* __restrict__ bbase, int n, int NE,
    int* __restrict__ rs, int* __restrict__ csr)
{
    __shared__ int cnt[256], pre[256], cnt2[256];
    int b = blockIdx.x, t = threadIdx.x;
    int s0 = bbase[b], s1 = bbase[b + 1];
    cnt[t] = 0; cnt2[t] = 0;
    __syncthreads();
    for (int i = s0 + t; i < s1; i += 256)
        atomicAdd(&cnt[tmp[i].y & 255], 1);
    __syncthreads();
    int v = cnt[t];
    pre[t] = v;
    __syncthreads();
    for (int off = 1; off < 256; off <<= 1) {
        int u = (t >= off) ? pre[t - off] : 0;
        __syncthreads();
        pre[t] += u;
        __syncthreads();
    }
    pre[t] -= v;   // exclusive
    __syncthreads();
    int dstid = b * 256 + t;
    if (dstid < n) rs[dstid] = s0 + pre[t];
    if (b == 0 && t == 0) rs[n] = NE;
    for (int i = s0 + t; i < s1; i += 256) {
        int2 e = tmp[i];
        int low = e.y & 255;
        int r = atomicAdd(&cnt2[low], 1);
        csr[s0 + pre[low] + r] = e.x;
    }
}

// ---------------- MFMA q~/k/v GEMM + tail blocks run prev-layer attn_out ------
// A fp32 -> fp16 LDS tile; W pre-transposed fp16 [n][k]; fp32 MFMA accumulate.
// Per-wave tile: 16 rows x 128 cols. mfma_f32_16x16x32_f16:
//   A-frag lane l: A[l&15][(l>>4)*8+i] ; B-frag: B[(l>>4)*8+i][l&15]
//   D lane l reg r: D[(l>>4)*4+r][l&15]
__global__ __launch_bounds__(256) void gemm_qkv(
    int nblk1,
    const float* __restrict__ A, int lda, int M,
    const _Float16* __restrict__ WT3,   // 3 matrices [128][128] fp16, n-major
    const float* __restrict__ b0, const float* __restrict__ b1, const float* __restrict__ b2,
    float* __restrict__ out,
    // prev-layer out-conv attention (tail blocks); unused when grid == nblk1
    const float* __restrict__ qo, const float* __restrict__ ko, const float* __restrict__ vo,
    const int* __restrict__ rs_cv, const int* __restrict__ csr_cv,
    const float* __restrict__ arel_o, const float* __restrict__ prel_o,
    const float* __restrict__ mrel_o, const float* __restrict__ Wa_o,
    const float* __restrict__ ba_o, float* __restrict__ outl)
{
    extern __shared__ char dynsm[];
    __shared__ float sms[4], sma[4];
    int tid = threadIdx.x;

    if ((int)blockIdx.x >= nblk1) {
        // ---------------- prev-layer out-conv scalar attention ----------------
        int node = blockIdx.x - nblk1;
        float qs = qo[node] * arel_o[0] * prel_o[0];
        int rs = rs_cv[node], re = rs_cv[node + 1];
        float s = 0.f, a = 0.f;
        for (int e = rs + tid; e < re; e += 256) {
            int si = csr_cv[e];
            float w = __expf(qs * ko[si]);
            s += w;
            a = fmaf(w, vo[si], a);
        }
        #pragma unroll
        for (int off = 32; off >= 1; off >>= 1) {
            s += __shfl_xor(s, off, 64);
            a += __shfl_xor(a, off, 64);
        }
        int lane = tid & 63, wid = tid >> 6;
        if (lane == 0) { sms[wid] = s; sma[wid] = a; }
        __syncthreads();
        if (tid == 0) {
            float S = sms[0] + sms[1] + sms[2] + sms[3];
            float A_ = sma[0] + sma[1] + sma[2] + sma[3];
            float agg = (S > 0.f) ? A_ / S : 0.f;
            agg *= mrel_o[0];
            outl[node] = gelu_tanh(agg) * Wa_o[0] + ba_o[0];
        }
        return;
    }

    _Float16 (*Af)[136] = (_Float16(*)[136])dynsm;   // 17408 B
    int row0 = blockIdx.x * 64;
    // stage A tile fp32 -> fp16
    #pragma unroll
    for (int i = 0; i < 8; i++) {
        int slot = tid + i * 256;            // 2048 float4 slots
        int r = slot >> 5, q = slot & 31;
        int rr = row0 + r;
        float4 v = make_float4(0.f, 0.f, 0.f, 0.f);
        if (rr < M) v = *(const float4*)(A + (size_t)rr * lda + q * 4);
        f16x4 h = { (_Float16)v.x, (_Float16)v.y, (_Float16)v.z, (_Float16)v.w };
        *(f16x4*)&Af[r][q * 4] = h;
    }
    __syncthreads();

    int lane = tid & 63, w = tid >> 6;
    int mr = lane & 15, g = lane >> 4;
    // a-frags for this wave's 16 rows, all 4 k-steps
    f16x8 afr[4];
    #pragma unroll
    for (int kk = 0; kk < 4; kk++)
        afr[kk] = *(const f16x8*)&Af[w * 16 + mr][kk * 32 + g * 8];

    const float* bs[3] = {b0, b1, b2};
    for (int jw = 0; jw < 3; jw++) {
        const _Float16* WT = WT3 + (size_t)jw * CH * CH;
        f32x4 acc[8] = {};
        #pragma unroll
        for (int kk = 0; kk < 4; kk++) {
            #pragma unroll
            for (int f = 0; f < 8; f++) {
                f16x8 bf = *(const f16x8*)(WT + (size_t)(f * 16 + mr) * CH + kk * 32 + g * 8);
                acc[f] = __builtin_amdgcn_mfma_f32_16x16x32_f16(afr[kk], bf, acc[f], 0, 0, 0);
            }
        }
        const float* bb = bs[jw];
        if (jw == 0) {
            #pragma unroll
            for (int f = 0; f < 8; f++) {
                int col = f * 16 + mr;
                float bias = bb[col];
                #pragma unroll
                for (int r = 0; r < 4; r++) {
                    int row = row0 + w * 16 + g * 4 + r;
                    if (row < M) out[(size_t)row * 256 + col] = acc[f][r] + bias;
                }
            }
        } else {
            char* kvb = (char*)out + 512 + (jw - 1) * 256;
            #pragma unroll
            for (int f = 0; f < 8; f++) {
                int col = f * 16 + mr;
                float bias = bb[col];
                #pragma unroll
                for (int r = 0; r < 4; r++) {
                    int row = row0 + w * 16 + g * 4 + r;
                    if (row < M)
                        *(_Float16*)(kvb + ((size_t)row << 10) + (size_t)col * 2) =
                            (_Float16)(acc[f][r] + bias);
                }
            }
        }
    }
}

// ---------------- Wa GEMM: c-side MFMA fp16, v-side fp32 vector ---------------
// Merged dual dispatch: blocks [0,nblk1) run c-side (MFMA), blocks >= nblk1
// run v-side (old vector path). All parameter selection is wave-uniform.
__global__ __launch_bounds__(256) void gemm128(
    int nblk1,
    // primary (c-side, MFMA)
    const float* __restrict__ A1, int lda1, const _Float16* __restrict__ W1h,
    const float* __restrict__ bias1, float* __restrict__ out1, int M1,
    const float* __restrict__ gate1, const float* __restrict__ xold1,
    const float* __restrict__ wk1, const float* __restrict__ bk1, float* __restrict__ ko1,
    const float* __restrict__ wv1, const float* __restrict__ bv1, float* __restrict__ vo1,
    // secondary (v-side, fp32 vector)
    const float* __restrict__ A2, int lda2, const float* __restrict__ W2,
    const float* __restrict__ bias2, float* __restrict__ out2, int M2,
    const float* __restrict__ gate2, const float* __restrict__ xold2,
    const float* __restrict__ wk2, const float* __restrict__ bk2, float* __restrict__ ko2)
{
    extern __shared__ char dynsm[];
    int tid = threadIdx.x;

    if ((int)blockIdx.x < nblk1) {
        // ======================= c-side: MFMA =======================
        _Float16 (*Af)[136] = (_Float16(*)[136])dynsm;
        int row0 = blockIdx.x * 64;
        #pragma unroll
        for (int i = 0; i < 8; i++) {
            int slot = tid + i * 256;
            int r = slot >> 5, q = slot & 31;
            int rr = row0 + r;
            float4 v = make_float4(0.f, 0.f, 0.f, 0.f);
            if (rr < M1) v = *(const float4*)(A1 + (size_t)rr * lda1 + q * 4);
            f16x4 h = { (_Float16)v.x, (_Float16)v.y, (_Float16)v.z, (_Float16)v.w };
            *(f16x4*)&Af[r][q * 4] = h;
        }
        __syncthreads();

        int lane = tid & 63, w = tid >> 6;
        int mr = lane & 15, g = lane >> 4;
        f16x8 afr[4];
        #pragma unroll
        for (int kk = 0; kk < 4; kk++)
            afr[kk] = *(const f16x8*)&Af[w * 16 + mr][kk * 32 + g * 8];

        f32x4 acc[8] = {};
        #pragma unroll
        for (int kk = 0; kk < 4; kk++) {
            #pragma unroll
            for (int f = 0; f < 8; f++) {
                f16x8 bf = *(const f16x8*)(W1h + (size_t)(f * 16 + mr) * CH + kk * 32 + g * 8);
                acc[f] = __builtin_amdgcn_mfma_f32_16x16x32_f16(afr[kk], bf, acc[f], 0, 0, 0);
            }
        }

        float gt = 1.f / (1.f + expf(-gate1[0]));
        float og = 1.f - gt;
        float pk[4] = {}, pv[4] = {};
        #pragma unroll
        for (int f = 0; f < 8; f++) {
            int col = f * 16 + mr;
            float bias = bias1[col];
            float wkc = wk1[col];
            float wvc = wv1[col];
            #pragma unroll
            for (int r = 0; r < 4; r++) {
                int row = row0 + w * 16 + g * 4 + r;
                if (row < M1) {
                    float v = acc[f][r] + bias;
                    v = gt * v + og * xold1[(size_t)row * 128 + col];
                    out1[(size_t)row * 128 + col] = v;
                    pk[r] = fmaf(v, wkc, pk[r]);
                    pv[r] = fmaf(v, wvc, pv[r]);
                }
            }
        }
        #pragma unroll
        for (int r = 0; r < 4; r++) {
            #pragma unroll
            for (int off = 1; off < 16; off <<= 1) {
                pk[r] += __shfl_xor(pk[r], off, 64);
                pv[r] += __shfl_xor(pv[r], off, 64);
            }
        }
        if (mr == 0) {
            #pragma unroll
            for (int r = 0; r < 4; r++) {
                int row = row0 + w * 16 + g * 4 + r;
                if (row < M1) {
                    ko1[row] = pk[r] + bk1[0];
                    vo1[row] = pv[r] + bv1[0];
                }
            }
        }
        return;
    }

    // ======================= v-side: fp32 vector =======================
    float (*As)[36]  = (float(*)[36])dynsm;                 // 9216 B
    float (*Bs)[128] = (float(*)[128])(dynsm + 64 * 36 * 4); // 16384 B
    const float* A    = A2;
    int lda           = lda2;
    const float* W    = W2;
    const float* bias = bias2;
    float* out        = out2;
    int M             = M2;
    const float* gate = gate2;
    const float* xold = xold2;
    const float* wk_o = wk2;
    const float* bk_o = bk2;
    float* ko         = ko2;

    int row0 = (blockIdx.x - nblk1) * 64;
    int tx = tid & 15;
    int ty = tid >> 4;
    float acc[4][8] = {};
    for (int k0 = 0; k0 < 128; k0 += 32) {
        __syncthreads();
        #pragma unroll
        for (int i = 0; i < 2; i++) {
            int slot = tid + i * 256;            // [0,512) float4 slots
            int r = slot >> 3, kq = slot & 7;
            int rr = row0 + r;
            float4 v = make_float4(0.f, 0.f, 0.f, 0.f);
            if (rr < M) v = *(const float4*)(A + (size_t)rr * lda + k0 + kq * 4);
            *(float4*)&As[r][kq * 4] = v;
        }
        #pragma unroll
        for (int i = 0; i < 4; i++) {
            int slot = tid + i * 256;            // [0,1024)
            int kr = slot >> 5, cq = slot & 31;
            *(float4*)&Bs[kr][cq * 4] = *(const float4*)(W + (size_t)(k0 + kr) * 128 + cq * 4);
        }
        __syncthreads();
        #pragma unroll
        for (int k4 = 0; k4 < 32; k4 += 4) {
            float4 av[4];
            #pragma unroll
            for (int i = 0; i < 4; i++)
                av[i] = *(const float4*)&As[ty * 4 + i][k4];
            #pragma unroll
            for (int kk = 0; kk < 4; kk++) {
                float4 bl = *(const float4*)&Bs[k4 + kk][tx * 4];
                float4 bh = *(const float4*)&Bs[k4 + kk][64 + tx * 4];
                float bb[8] = {bl.x, bl.y, bl.z, bl.w, bh.x, bh.y, bh.z, bh.w};
                #pragma unroll
                for (int i = 0; i < 4; i++) {
                    float a = ((const float*)&av[i])[kk];
                    #pragma unroll
                    for (int j = 0; j < 8; j++)
                        acc[i][j] = fmaf(a, bb[j], acc[i][j]);
                }
            }
        }
    }
    float gt = 1.f / (1.f + expf(-gate[0]));
    float og = 1.f - gt;
    float wkr[8];
    #pragma unroll
    for (int j = 0; j < 4; j++) {
        wkr[j]     = wk_o[tx * 4 + j];
        wkr[4 + j] = wk_o[64 + tx * 4 + j];
    }
    #pragma unroll
    for (int i = 0; i < 4; i++) {
        int r = row0 + ty * 4 + i;
        if (r >= M) continue;   // uniform across each 16-lane group
        float vals[8];
        #pragma unroll
        for (int j = 0; j < 4; j++) {
            float v0 = acc[i][j]     + bias[tx * 4 + j];
            float v1 = acc[i][4 + j] + bias[64 + tx * 4 + j];
            v0 = gt * v0 + og * xold[(size_t)r * 128 + tx * 4 + j];
            v1 = gt * v1 + og * xold[(size_t)r * 128 + 64 + tx * 4 + j];
            vals[j] = v0;
            vals[4 + j] = v1;
        }
        float* op = out + (size_t)r * 128;
        *(float4*)(op + tx * 4)      = make_float4(vals[0], vals[1], vals[2], vals[3]);
        *(float4*)(op + 64 + tx * 4) = make_float4(vals[4], vals[5], vals[6], vals[7]);
        float pk = 0.f;
        #pragma unroll
        for (int j = 0; j < 8; j++) pk = fmaf(vals[j], wkr[j], pk);
        #pragma unroll
        for (int off = 1; off < 16; off <<= 1)
            pk += __shfl_xor(pk, off, 64);
        if (tx == 0) ko[r] = pk + bk_o[0];
    }
}

// ---------------- pipelined fp16-payload edge accumulation --------------------
__device__ __forceinline__ void gather_pipe(
    const float* __restrict__ xqkv, const int* __restrict__ csr,
    int e0, int e1, int g, int j, const float* q8,
    float& s_io, float acc[8])
{
    int lane = threadIdx.x & 63;
    float s = s_io;
    const char* base = (const char*)xqkv;
    for (int cs = e0; cs < e1; cs += 64) {
        int n = e1 - cs; if (n > 64) n = 64;
        int nm1 = n - 1;
        int idx0 = 0;
        if (lane < n) idx0 = csr[cs + lane];
        int R = (n + 7) >> 3;   // rounds of 8 edges (2 per group)

        uint4 ak0, av0, ak1, av1;   // buffer A (even rounds, 2 edges)
        uint4 bk0, bv0, bk1, bv1;   // buffer B (odd rounds)

#define LD2(E0_, E1_, K0, V0, K1, V1) { \
            int i0_ = __shfl(idx0, min((E0_), nm1), 64); \
            int i1_ = __shfl(idx0, min((E1_), nm1), 64); \
            const uint4* p0_ = (const uint4*)(base + ((size_t)i0_ << 10) + 512 + 16 * j); \
            const uint4* p1_ = (const uint4*)(base + ((size_t)i1_ << 10) + 512 + 16 * j); \
            K0 = p0_[0]; V0 = p0_[16]; \
            K1 = p1_[0]; V1 = p1_[16]; }

#define CMP(E0_, E1_, K0, V0, K1, V1) { \
            float k0f[8], k1f[8], v0f[8], v1f[8]; \
            h8_to_f8(K0, k0f); h8_to_f8(K1, k1f); \
            float d0_ = dot8f(q8, k0f); \
            float d1_ = dot8f(q8, k1f); \
            d0_ += __shfl_xor(d0_, 1, 64); d1_ += __shfl_xor(d1_, 1, 64); \
            d0_ += __shfl_xor(d0_, 2, 64); d1_ += __shfl_xor(d1_, 2, 64); \
            float w0_ = ((E0_) < n) ? __expf(d0_) : 0.f; \
            float w1_ = ((E1_) < n) ? __expf(d1_) : 0.f; \
            s += w0_ + w1_; \
            h8_to_f8(V0, v0f); h8_to_f8(V1, v1f); \
            acc[0] = fmaf(w0_, v0f[0], acc[0]); acc[0] = fmaf(w1_, v1f[0], acc[0]); \
            acc[1] = fmaf(w0_, v0f[1], acc[1]); acc[1] = fmaf(w1_, v1f[1], acc[1]); \
            acc[2] = fmaf(w0_, v0f[2], acc[2]); acc[2] = fmaf(w1_, v1f[2], acc[2]); \
            acc[3] = fmaf(w0_, v0f[3], acc[3]); acc[3] = fmaf(w1_, v1f[3], acc[3]); \
            acc[4] = fmaf(w0_, v0f[4], acc[4]); acc[4] = fmaf(w1_, v1f[4], acc[4]); \
            acc[5] = fmaf(w0_, v0f[5], acc[5]); acc[5] = fmaf(w1_, v1f[5], acc[5]); \
            acc[6] = fmaf(w0_, v0f[6], acc[6]); acc[6] = fmaf(w1_, v1f[6], acc[6]); \
            acc[7] = fmaf(w0_, v0f[7], acc[7]); acc[7] = fmaf(w1_, v1f[7], acc[7]); }

        // prefetch round 0 (A) and round 1 (B)
        LD2(g, g + 4, ak0, av0, ak1, av1);
        if (R > 1) LD2(g + 8, g + 12, bk0, bv0, bk1, bv1);

        for (int r = 0; r < R; r += 2) {
            int er = g + 8 * r;
            CMP(er, er + 4, ak0, av0, ak1, av1);
            if (r + 2 < R) {
                int ep = g + 8 * (r + 2);
                LD2(ep, ep + 4, ak0, av0, ak1, av1);
            }
            if (r + 1 < R) {
                int eo = g + 8 * (r + 1);
                CMP(eo, eo + 4, bk0, bv0, bk1, bv1);
                if (r + 3 < R) {
                    int eq = g + 8 * (r + 3);
                    LD2(eq, eq + 4, bk0, bv0, bk1, bv1);
                }
            }
        }
#undef LD2
#undef CMP
    }
    s_io = s;
}

// ---------------- unified attention: cv blocks [0,256) + cc blocks -------------
__global__ __launch_bounds__(256) void attn_uni(
    float* xqkv,
    const float* __restrict__ xv, const float* __restrict__ wqt,
    const float* __restrict__ bqt,
    const int* __restrict__ rs_cc, const int* __restrict__ csr_cc,
    const int* __restrict__ rs_cv, const int* __restrict__ csr_cv,
    const float* __restrict__ mrel_cc, const float* __restrict__ mrel_cv,
    float* __restrict__ aggv, int n_c)
{
    __shared__ float smem[800];   // 3.2 KB, carved per role
    int lane = threadIdx.x & 63, wid = threadIdx.x >> 6;
    int g = lane >> 4, j = lane & 15;

    if (blockIdx.x < N_V) {
        // ---------------- cv node ----------------
        int node = blockIdx.x;
        float* qrow = smem;          // [128]
        float* sm_s = smem + 128;    // [4][4]
        float* sm_a = smem + 144;    // [4][128]
        float* orow = smem + 656;    // [144]
        if (wid < 2) {
            int col = wid * 64 + lane;
            float a = bqt[col];
            const float* xr = xv + (size_t)node * 128;
            for (int k = 0; k < 128; k++)
                a = fmaf(xr[k], wqt[(size_t)k * 128 + col], a);
            qrow[col] = a;
        }
        __syncthreads();
        float q8[8];
        *(float4*)&q8[0] = *(const float4*)&qrow[8 * j];
        *(float4*)&q8[4] = *(const float4*)&qrow[8 * j + 4];
        int rs = rs_cv[node], re = rs_cv[node + 1];
        int cnt = re - rs;
        int per = (cnt + 3) >> 2;
        int e0 = rs + wid * per, e1 = min(e0 + per, re);
        float s = 0.f;
        float acc[8] = {};
        gather_pipe(xqkv, csr_cv, e0, e1, g, j, q8, s, acc);
        #pragma unroll
        for (int i = 0; i < 8; i++) {
            acc[i] += __shfl_xor(acc[i], 16, 64);
            acc[i] += __shfl_xor(acc[i], 32, 64);
        }
        s += __shfl_xor(s, 16, 64);
        s += __shfl_xor(s, 32, 64);
        if (g == 0) {
            *(float4*)&sm_a[wid * 128 + 8 * j]     = make_float4(acc[0], acc[1], acc[2], acc[3]);
            *(float4*)&sm_a[wid * 128 + 8 * j + 4] = make_float4(acc[4], acc[5], acc[6], acc[7]);
            if ((j & 3) == 0) sm_s[wid * 4 + (j >> 2)] = s;
        }
        __syncthreads();
        if (threadIdx.x < 64) {
            int lp = 2 * lane;
            int h = lp >> 5;
            float S = 0.f, AX = 0.f, AY = 0.f;
            #pragma unroll
            for (int i = 0; i < 4; i++) {
                S  += sm_s[i * 4 + h];
                float2 a2 = *(const float2*)&sm_a[i * 128 + lp];
                AX += a2.x;
                AY += a2.y;
            }
            float inv = (S > 0.f) ? 1.f / S : 0.f;
            int off = lp + 4 * h;   // padded
            orow[off]     = AX * inv;
            orow[off + 1] = AY * inv;
            int eo = lp & 31;
            const float* mr = mrel_cv + h * 1024 + eo;
            const float* rb = orow + 36 * h;
            float t0 = 0.f, t1 = 0.f;
            #pragma unroll
            for (int d = 0; d < 32; d++) {
                float a = rb[d];
                t0 = fmaf(a, mr[d * 32], t0);
                t1 = fmaf(a, mr[d * 32 + 1], t1);
            }
            aggv[(size_t)node * 128 + lp]     = gelu_tanh(t0);
            aggv[(size_t)node * 128 + lp + 1] = gelu_tanh(t1);
        }
    } else {
        // ---------------- cc nodes (4 per block, 1 wave each) ----------------
        float* rowbuf = smem;        // [4][144]
        int node = (blockIdx.x - N_V) * 4 + wid;
        if (node >= n_c) return;
        const float* qp = xqkv + (size_t)node * 256 + 8 * j;
        float q8[8];
        *(float4*)&q8[0] = *(const float4*)qp;
        *(float4*)&q8[4] = *(const float4*)(qp + 4);
        int rs = rs_cc[node], re = rs_cc[node + 1];
        float s = 0.f;
        float acc[8] = {};
        gather_pipe(xqkv, csr_cc, rs, re, g, j, q8, s, acc);
        #pragma unroll
        for (int i = 0; i < 8; i++) {
            acc[i] += __shfl_xor(acc[i], 16, 64);
            acc[i] += __shfl_xor(acc[i], 32, 64);
        }
        s += __shfl_xor(s, 16, 64);
        s += __shfl_xor(s, 32, 64);
        float inv = (s > 0.f) ? 1.f / s : 0.f;
        float* rb_w = rowbuf + wid * 144;
        if (g == 0) {
            int off = 8 * j + 4 * (j >> 2);   // +4 pad per head
            float4 o0 = make_float4(acc[0] * inv, acc[1] * inv, acc[2] * inv, acc[3] * inv);
            float4 o1 = make_float4(acc[4] * inv, acc[5] * inv, acc[6] * inv, acc[7] * inv);
            *(float4*)&rb_w[off]     = o0;
            *(float4*)&rb_w[off + 4] = o1;
        }
        // intra-wave DS ordering: no barrier needed
        int lp = 2 * lane;
        int h = lp >> 5, eo = lp & 31;
        const float* mr = mrel_cc + h * 1024 + eo;
        const float* rb = rb_w + 36 * h;
        float t0 = 0.f, t1 = 0.f;
        #pragma unroll
        for (int d = 0; d < 32; d++) {
            float a = rb[d];
            t0 = fmaf(a, mr[d * 32], t0);
            t1 = fmaf(a, mr[d * 32 + 1], t1);
        }
        float2 o = make_float2(gelu_tanh(t0), gelu_tanh(t1));
        *(float2*)(xqkv + (size_t)node * 256 + lp) = o;
    }
}

// ---------------- out-conv scalar attention (standalone, last layer) -----------
__global__ __launch_bounds__(256) void attn_out(
    const float* __restrict__ qo, const float* __restrict__ ko, const float* __restrict__ vo,
    const int* __restrict__ rowstart, const int* __restrict__ csr,
    const float* __restrict__ arel_o, const float* __restrict__ prel_o,
    const float* __restrict__ mrel_o, const float* __restrict__ Wa_o,
    const float* __restrict__ ba_o, float* __restrict__ outl)
{
    int node = blockIdx.x;
    float qs = qo[node] * arel_o[0] * prel_o[0];
    int rs = rowstart[node], re = rowstart[node + 1];
    float s = 0.f, a = 0.f;
    for (int e = rs + (int)threadIdx.x; e < re; e += 256) {
        int si = csr[e];
        float w = __expf(qs * ko[si]);
        s += w;
        a = fmaf(w, vo[si], a);
    }
    #pragma unroll
    for (int off = 32; off >= 1; off >>= 1) {
        s += __shfl_xor(s, off, 64);
        a += __shfl_xor(a, off, 64);
    }
    __shared__ float sms[4], sma[4];
    int lane = threadIdx.x & 63, wid = threadIdx.x >> 6;
    if (lane == 0) { sms[wid] = s; sma[wid] = a; }
    __syncthreads();
    if (threadIdx.x == 0) {
        float S = sms[0] + sms[1] + sms[2] + sms[3];
        float A = sma[0] + sma[1] + sma[2] + sma[3];
        float agg = (S > 0.f) ? A / S : 0.f;
        agg *= mrel_o[0];
        outl[node] = gelu_tanh(agg) * Wa_o[0] + ba_o[0];
    }
}

// ---------------- final head: JK-max -> node_fc -> MLP ------------------------
__global__ void final_head(const float* __restrict__ outs,
    const float* __restrict__ fc_W, const float* __restrict__ fc_b,
    const float* __restrict__ W1, const float* __restrict__ b1,
    const float* __restrict__ W2, const float* __restrict__ b2,
    float* __restrict__ out)
{
    int b = threadIdx.x;
    if (b >= 64) return;
    float h = fc_b[0];
    #pragma unroll
    for (int v = 0; v < 4; v++) {
        int n = b * 4 + v;
        float jk = fmaxf(fmaxf(outs[0 * N_V + n], outs[1 * N_V + n]), outs[2 * N_V + n]);
        h = fmaf(jk, fc_W[v], h);
    }
    h = gelu_tanh(h);
    float h0 = gelu_tanh(h * W1[0] + b1[0]);
    float h1 = gelu_tanh(h * W1[1] + b1[1]);
    out[b] = h0 * W2[0] + h1 * W2[1] + b2[0];
}

// ---------------- orchestration ----------------------------------------------
extern "C" void kernel_launch(void* const* d_in, const int* in_sizes, int n_in,
                              void* d_out, int out_size, void* d_ws, size_t ws_size,
                              hipStream_t stream) {
    (void)in_sizes; (void)n_in; (void)out_size; (void)ws_size;
    const float* x_cell  = (const float*)d_in[0];
    const float* x_vcell = (const float*)d_in[1];
    const float* Wk   = (const float*)d_in[2];
    const float* bk   = (const float*)d_in[3];
    const float* Wq   = (const float*)d_in[4];
    const float* bq   = (const float*)d_in[5];
    const float* Wv   = (const float*)d_in[6];
    const float* bv   = (const float*)d_in[7];
    const float* Wa   = (const float*)d_in[8];
    const float* ba   = (const float*)d_in[9];
    const float* skip = (const float*)d_in[10];
    const float* arel = (const float*)d_in[11];
    const float* mrel = (const float*)d_in[12];
    const float* prel = (const float*)d_in[13];
    const float* Wk_o = (const float*)d_in[14];
    const float* bk_o = (const float*)d_in[15];
    const float* Wq_o = (const float*)d_in[16];
    const float* bq_o = (const float*)d_in[17];
    const float* Wv_o = (const float*)d_in[18];
    const float* bv_o = (const float*)d_in[19];
    const float* Wa_o = (const float*)d_in[20];
    const float* ba_o = (const float*)d_in[21];
    const float* arel_o = (const float*)d_in[22];
    const float* mrel_o = (const float*)d_in[23];
    const float* prel_o = (const float*)d_in[24];
    const float* fc_W  = (const float*)d_in[25];
    const float* fc_b  = (const float*)d_in[26];
    const float* mlp_W1 = (const float*)d_in[27];
    const float* mlp_b1 = (const float*)d_in[28];
    const float* mlp_W2 = (const float*)d_in[29];
    const float* mlp_b2 = (const float*)d_in[30];
    const int* src_cc = (const int*)d_in[31];
    const int* dst_cc = (const int*)d_in[32];
    const int* src_cv = (const int*)d_in[33];
    const int* dst_cv = (const int*)d_in[34];

    // workspace carve-up (256B aligned)
    char* p = (char*)d_ws;
    auto alloc = [&](size_t bytes) -> char* {
        uintptr_t q = ((uintptr_t)p + 255) & ~(uintptr_t)255;
        p = (char*)(q + bytes);
        return (char*)q;
    };
    float* WQT  = (float*)alloc(sizeof(float) * NL * 2 * CH * CH);
    float* BQT  = (float*)alloc(sizeof(float) * NL * 2 * CH);
    _Float16* WT16 = (_Float16*)alloc(sizeof(_Float16) * NL * 4 * CH * CH);
    float* XC   = (float*)alloc(sizeof(float) * (size_t)N_C * CH);
    float* XV   = (float*)alloc(sizeof(float) * (size_t)N_V * CH);
    float* XQKV = (float*)alloc(sizeof(float) * (size_t)N_C * 256);  // [q~ f32 | k,v fp16]
    float* AGGV = (float*)alloc(sizeof(float) * (size_t)N_V * CH);
    float* KO   = (float*)alloc(sizeof(float) * N_C);
    float* VO   = (float*)alloc(sizeof(float) * N_C);
    float* QO   = (float*)alloc(sizeof(float) * N_V);
    float* OUTS = (float*)alloc(sizeof(float) * NL * N_V);
    // CSR-build scratch (hist region zeroed in one memset)
    int* bhist    = (int*)alloc(sizeof(int) * 512);
    int* bhist_cc = bhist;
    int* bhist_cv = bhist + 256;
    int* bbase_cc = (int*)alloc(sizeof(int) * 257);
    int* cur_cc   = (int*)alloc(sizeof(int) * 256);
    int* cur_cv   = (int*)alloc(sizeof(int) * 256);
    int* rs_cc    = (int*)alloc(sizeof(int) * (N_C + 1));
    int* rs_cv    = (int*)alloc(sizeof(int) * (N_V + 1));
    int* csr_cc   = (int*)alloc(sizeof(int) * NE1);
    int* csr_cv   = (int*)alloc(sizeof(int) * NE2);
    int2* tmp_cc  = (int2*)alloc(sizeof(int2) * NE1);

    // ---- setup: composed weights + fp16 weights + CSR ----
    compose_wq<<<CDIV(NL * 2 * (CH + 1) * CH, 256), 256, 0, stream>>>(
        Wq, bq, arel, prel, WQT, BQT);
    cvt_w16<<<NL * 4, 128, 0, stream>>>(WQT, Wk, Wv, Wa, WT16);
    hipMemsetAsync(bhist, 0, sizeof(int) * 512, stream);
    bucket_hist<<<CDIV(NE1, EPB), 256, 0, stream>>>(dst_cc, NE1, 8, bhist_cc);
    bucket_hist<<<CDIV(NE2, EPB), 256, 0, stream>>>(dst_cv, NE2, 0, bhist_cv);
    scan256<<<1, 256, 0, stream>>>(bhist_cc, bbase_cc, cur_cc);
    scan256<<<1, 256, 0, stream>>>(bhist_cv, rs_cv, cur_cv);   // rs_cv IS the cv row starts
    partition_edges<true ><<<CDIV(NE1, EPB), 256, 0, stream>>>(src_cc, dst_cc, NE1, 8,
                                                               cur_cc, tmp_cc, nullptr);
    partition_edges<false><<<CDIV(NE2, EPB), 256, 0, stream>>>(src_cv, dst_cv, NE2, 0,
                                                               cur_cv, nullptr, csr_cv);
    bucket_finalize<<<CDIV(N_C, 256), 256, 0, stream>>>(tmp_cc, bbase_cc, N_C, NE1,
                                                        rs_cc, csr_cc);

    const int gb_c = CDIV(N_C, 64);             // 938
    const int gb_v = CDIV(N_V, 64);             // 4
    const int gb_attn = N_V + CDIV(N_C, 4);     // 256 cv + 15000 cc blocks
    const int SM_QKV = 64 * 136 * 2;            // 17408 B
    const int SM_128 = 64 * 36 * 4 + 32 * 128 * 4;  // 25600 B (>= MFMA's 17408)

    for (int li = 0; li < NL; li++) {
        const float* xc_src = (li == 0) ? x_cell : XC;
        const float* xv_src = (li == 0) ? x_vcell : XV;
        size_t w1 = (size_t)(li * 2 + 1) * CH * CH;
        int b0 = (li * 2) * CH, b1 = (li * 2 + 1) * CH;
        const _Float16* WT_qkv = WT16 + (size_t)(li * 4) * CH * CH;      // q~,k,v
        const _Float16* WT_a   = WT16 + (size_t)(li * 4 + 3) * CH * CH;  // Wa c-side

        // fused q~/k/v MFMA GEMM; layers >0 append prev-layer out-conv attn tail
        int tail = (li > 0) ? N_V : 0;
        gemm_qkv<<<gb_c + tail, 256, SM_QKV, stream>>>(
            gb_c, xc_src, 128, N_C,
            WT_qkv,
            BQT + b0, bk + b0, bv + b0, XQKV,
            QO, KO, VO, rs_cv, csr_cv,
            arel_o + (li - 1), prel_o + (li - 1), mrel_o + (li - 1),
            Wa_o + (li - 1), ba_o + (li - 1),
            (li > 0) ? (OUTS + (li - 1) * N_V) : nullptr);

        // unified attention: cv (inline q~v projection, 4 waves/node) + cc
        attn_uni<<<gb_attn, 256, 0, stream>>>(
            XQKV, xv_src, WQT + w1, BQT + b1,
            rs_cc, csr_cc, rs_cv, csr_cv,
            mrel + (size_t)(li * 2) * NH * HD * HD,
            mrel + (size_t)(li * 2 + 1) * NH * HD * HD,
            AGGV, N_C);

        // merged Wa GEMMs (c-side MFMA + v-side vector) with skip epilogue;
        // c-side fuses out-conv k/v projections, v-side fuses q projection
        gemm128<<<gb_c + gb_v, 256, SM_128, stream>>>(
            gb_c,
            XQKV, 256, WT_a, ba + b0, XC, N_C,
            skip + li * 2, xc_src,
            Wk_o + li * CH, bk_o + li, KO,
            Wv_o + li * CH, bv_o + li, VO,
            AGGV, 128, Wa + w1, ba + b1, XV, N_V,
            skip + li * 2 + 1, xv_src,
            Wq_o + li * CH, bq_o + li, QO);
    }

    // last layer's out-conv attention, then final head
    attn_out<<<N_V, 256, 0, stream>>>(QO, KO, VO, rs_cv, csr_cv,
                                      arel_o + (NL - 1), prel_o + (NL - 1), mrel_o + (NL - 1),
                                      Wa_o + (NL - 1), ba_o + (NL - 1), OUTS + (NL - 1) * N_V);
    final_head<<<1, 64, 0, stream>>>(OUTS, fc_W, fc_b, mlp_W1, mlp_b1, mlp_W2, mlp_b2,
                                     (float*)d_out);
}

// Round 4
// 810.932 us; speedup vs baseline: 1.2578x; 1.0303x over previous
//
#include <hip/hip_runtime.h>
#include <hip/hip_fp16.h>
#include <math.h>
#include <stdint.h>

#define N_C 60000
#define N_V 256
#define CH 128
#define NH 4
#define HD 32
#define NL 3
#define NE1 600000
#define NE2 240000

#define CDIV(a,b) (((a)+(b)-1)/(b))
#define EPB 1024   // elems per block in counting-sort kernels

// Node state layout:
//   XQ  [N_C][128] f32 : q~ (layer in) / agg (layer out)
//   KV8 [N_C][256] B   : k fp8-e4m3 x128 | v fp8-e4m3 x128  (storage only)

typedef _Float16 f16x8 __attribute__((ext_vector_type(8)));
typedef _Float16 f16x4 __attribute__((ext_vector_type(4)));
typedef float f32x4 __attribute__((ext_vector_type(4)));
typedef float f32x2 __attribute__((ext_vector_type(2)));

__device__ __forceinline__ float gelu_tanh(float x) {
    float x3 = x * x * x;
    float t = tanhf(0.7978845608028654f * (x + 0.044715f * x3));
    return 0.5f * x * (1.0f + t);
}

__device__ __forceinline__ void fp8x8_to_f32(uint2 w, float* f) {
    f32x2 a = __builtin_amdgcn_cvt_pk_f32_fp8(w.x, false);
    f32x2 b = __builtin_amdgcn_cvt_pk_f32_fp8(w.x, true);
    f32x2 c = __builtin_amdgcn_cvt_pk_f32_fp8(w.y, false);
    f32x2 d = __builtin_amdgcn_cvt_pk_f32_fp8(w.y, true);
    f[0] = a.x; f[1] = a.y; f[2] = b.x; f[3] = b.y;
    f[4] = c.x; f[5] = c.y; f[6] = d.x; f[7] = d.y;
}

__device__ __forceinline__ float dot8f(const float* q, const float* k) {
    float d = q[0] * k[0];
    d = fmaf(q[1], k[1], d);
    d = fmaf(q[2], k[2], d);
    d = fmaf(q[3], k[3], d);
    d = fmaf(q[4], k[4], d);
    d = fmaf(q[5], k[5], d);
    d = fmaf(q[6], k[6], d);
    d = fmaf(q[7], k[7], d);
    return d;
}

// ---------------- weight composition: W~q = Wq . arel  (prel/sqrt(D) folded) ---
__global__ __launch_bounds__(256) void compose_wq(
    const float* __restrict__ Wq, const float* __restrict__ bq,
    const float* __restrict__ arel, const float* __restrict__ prel,
    float* __restrict__ WQT, float* __restrict__ BQT)
{
    int gid = blockIdx.x * blockDim.x + threadIdx.x;
    const int total = NL * 2 * (CH + 1) * CH;
    if (gid >= total) return;
    int li2 = gid / ((CH + 1) * CH);
    int rem = gid % ((CH + 1) * CH);
    int c   = rem / CH;          // 0..CH ; CH => bias row
    int col = rem % CH;
    int h = col >> 5, d = col & 31;
    const float* ar = arel + (li2 * NH + h) * (HD * HD) + d * HD;  // [e]
    float scale = prel[li2 * NH + h] * 0.17677669529663687f;       // prel/sqrt(32)
    const float* src = (c < CH) ? (Wq + ((size_t)li2 * CH + c) * CH + h * HD)
                                : (bq + li2 * CH + h * HD);
    float acc = 0.f;
    #pragma unroll
    for (int e = 0; e < HD; e++) acc = fmaf(src[e], ar[e], acc);
    acc *= scale;
    if (c < CH) WQT[((size_t)li2 * CH + c) * CH + col] = acc;
    else        BQT[li2 * CH + col] = acc;
}

// ---------------- weight fp16 transpose: WT16[b][n][k] = W[k][n] --------------
// b = li*4 + w ; w: 0=WQT(c-side) 1=Wk 2=Wv 3=Wa(c-side)
__global__ __launch_bounds__(128) void cvt_w16(
    const float* __restrict__ WQT, const float* __restrict__ Wk,
    const float* __restrict__ Wv, const float* __restrict__ Wa,
    _Float16* __restrict__ WT16)
{
    int b = blockIdx.x;
    int li = b >> 2, w = b & 3;
    size_t off = (size_t)(li * 2) * CH * CH;
    const float* src = (w == 0) ? (WQT + off)
                     : (w == 1) ? (Wk + off)
                     : (w == 2) ? (Wv + off)
                                : (Wa + off);
    _Float16* dst = WT16 + (size_t)b * CH * CH;
    int n = threadIdx.x;
    for (int k = 0; k < CH; k++)
        dst[n * CH + k] = (_Float16)src[k * CH + n];
}

// ================= CSR build: two-level LDS counting sort =====================
__global__ __launch_bounds__(256) void bucket_hist(const int* __restrict__ dst, int E,
                                                   int shift, int* __restrict__ bhist)
{
    __shared__ int h[256];
    int t = threadIdx.x;
    h[t] = 0;
    __syncthreads();
    int i0 = blockIdx.x * EPB, i1 = min(i0 + EPB, E);
    for (int i = i0 + t; i < i1; i += 256)
        atomicAdd(&h[(dst[i] >> shift) & 255], 1);
    __syncthreads();
    if (h[t] > 0) atomicAdd(&bhist[t], h[t]);
}

__global__ __launch_bounds__(256) void scan256(const int* __restrict__ h,
                                               int* __restrict__ base, int* __restrict__ cur)
{
    __shared__ int p[256];
    int t = threadIdx.x;
    int v = h[t];
    p[t] = v;
    __syncthreads();
    for (int off = 1; off < 256; off <<= 1) {
        int u = (t >= off) ? p[t - off] : 0;
        __syncthreads();
        p[t] += u;
        __syncthreads();
    }
    base[t] = p[t] - v;
    cur[t]  = p[t] - v;
    if (t == 255) base[256] = p[255];
}

template<bool PAIR>
__global__ __launch_bounds__(256) void partition_edges(
    const int* __restrict__ src, const int* __restrict__ dst, int E, int shift,
    int* __restrict__ cur, int2* __restrict__ tmp_pair, int* __restrict__ out_src)
{
    __shared__ int cnt[256], base[256], cnt2[256];
    int t = threadIdx.x;
    cnt[t] = 0; cnt2[t] = 0;
    __syncthreads();
    int i0 = blockIdx.x * EPB, i1 = min(i0 + EPB, E);
    for (int i = i0 + t; i < i1; i += 256)
        atomicAdd(&cnt[(dst[i] >> shift) & 255], 1);
    __syncthreads();
    if (cnt[t] > 0) base[t] = atomicAdd(&cur[t], cnt[t]);
    __syncthreads();
    for (int i = i0 + t; i < i1; i += 256) {
        int d = dst[i];
        int dig = (d >> shift) & 255;
        int r = atomicAdd(&cnt2[dig], 1);
        int pos = base[dig] + r;
        if constexpr (PAIR) tmp_pair[pos] = make_int2(src[i], d);
        else                out_src[pos] = src[i];
    }
}

__global__ __launch_bounds__(256) void bucket_finalize(
    const int2* __restrict__ tmp, const int* __restrict__ bbase, int n, int NE,
    int* __restrict__ rs, int* __restrict__ csr)
{
    __shared__ int cnt[256], pre[256], cnt2[256];
    int b = blockIdx.x, t = threadIdx.x;
    int s0 = bbase[b], s1 = bbase[b + 1];
    cnt[t] = 0; cnt2[t] = 0;
    __syncthreads();
    for (int i = s0 + t; i < s1; i += 256)
        atomicAdd(&cnt[tmp[i].y & 255], 1);
    __syncthreads();
    int v = cnt[t];
    pre[t] = v;
    __syncthreads();
    for (int off = 1; off < 256; off <<= 1) {
        int u = (t >= off) ? pre[t - off] : 0;
        __syncthreads();
        pre[t] += u;
        __syncthreads();
    }
    pre[t] -= v;   // exclusive
    __syncthreads();
    int dstid = b * 256 + t;
    if (dstid < n) rs[dstid] = s0 + pre[t];
    if (b == 0 && t == 0) rs[n] = NE;
    for (int i = s0 + t; i < s1; i += 256) {
        int2 e = tmp[i];
        int low = e.y & 255;
        int r = atomicAdd(&cnt2[low], 1);
        csr[s0 + pre[low] + r] = e.x;
    }
}

// ---------------- MFMA q~/k/v GEMM + tail blocks run prev-layer attn_out ------
// A fp32 -> fp16 LDS tile; W pre-transposed fp16 [n][k]; fp32 MFMA accumulate.
// q~ stored f32 to XQ; k,v packed to fp8-e4m3 in KV8 (shfl-pair + cvt_pk).
__global__ __launch_bounds__(256) void gemm_qkv(
    int nblk1,
    const float* __restrict__ A, int lda, int M,
    const _Float16* __restrict__ WT3,   // 3 matrices [128][128] fp16, n-major
    const float* __restrict__ b0, const float* __restrict__ b1, const float* __restrict__ b2,
    float* __restrict__ out, unsigned char* __restrict__ kv8,
    // prev-layer out-conv attention (tail blocks); unused when grid == nblk1
    const float* __restrict__ qo, const float* __restrict__ ko, const float* __restrict__ vo,
    const int* __restrict__ rs_cv, const int* __restrict__ csr_cv,
    const float* __restrict__ arel_o, const float* __restrict__ prel_o,
    const float* __restrict__ mrel_o, const float* __restrict__ Wa_o,
    const float* __restrict__ ba_o, float* __restrict__ outl)
{
    extern __shared__ char dynsm[];
    __shared__ float sms[4], sma[4];
    int tid = threadIdx.x;

    if ((int)blockIdx.x >= nblk1) {
        // ---------------- prev-layer out-conv scalar attention ----------------
        int node = blockIdx.x - nblk1;
        float qs = qo[node] * arel_o[0] * prel_o[0];
        int rs = rs_cv[node], re = rs_cv[node + 1];
        float s = 0.f, a = 0.f;
        for (int e = rs + tid; e < re; e += 256) {
            int si = csr_cv[e];
            float w = __expf(qs * ko[si]);
            s += w;
            a = fmaf(w, vo[si], a);
        }
        #pragma unroll
        for (int off = 32; off >= 1; off >>= 1) {
            s += __shfl_xor(s, off, 64);
            a += __shfl_xor(a, off, 64);
        }
        int lane = tid & 63, wid = tid >> 6;
        if (lane == 0) { sms[wid] = s; sma[wid] = a; }
        __syncthreads();
        if (tid == 0) {
            float S = sms[0] + sms[1] + sms[2] + sms[3];
            float A_ = sma[0] + sma[1] + sma[2] + sma[3];
            float agg = (S > 0.f) ? A_ / S : 0.f;
            agg *= mrel_o[0];
            outl[node] = gelu_tanh(agg) * Wa_o[0] + ba_o[0];
        }
        return;
    }

    _Float16 (*Af)[136] = (_Float16(*)[136])dynsm;   // 17408 B
    int row0 = blockIdx.x * 64;
    // stage A tile fp32 -> fp16
    #pragma unroll
    for (int i = 0; i < 8; i++) {
        int slot = tid + i * 256;            // 2048 float4 slots
        int r = slot >> 5, q = slot & 31;
        int rr = row0 + r;
        float4 v = make_float4(0.f, 0.f, 0.f, 0.f);
        if (rr < M) v = *(const float4*)(A + (size_t)rr * lda + q * 4);
        f16x4 h = { (_Float16)v.x, (_Float16)v.y, (_Float16)v.z, (_Float16)v.w };
        *(f16x4*)&Af[r][q * 4] = h;
    }
    __syncthreads();

    int lane = tid & 63, w = tid >> 6;
    int mr = lane & 15, g = lane >> 4;
    // a-frags for this wave's 16 rows, all 4 k-steps
    f16x8 afr[4];
    #pragma unroll
    for (int kk = 0; kk < 4; kk++)
        afr[kk] = *(const f16x8*)&Af[w * 16 + mr][kk * 32 + g * 8];

    const float* bs[3] = {b0, b1, b2};
    for (int jw = 0; jw < 3; jw++) {
        const _Float16* WT = WT3 + (size_t)jw * CH * CH;
        f32x4 acc[8] = {};
        #pragma unroll
        for (int kk = 0; kk < 4; kk++) {
            #pragma unroll
            for (int f = 0; f < 8; f++) {
                f16x8 bf = *(const f16x8*)(WT + (size_t)(f * 16 + mr) * CH + kk * 32 + g * 8);
                acc[f] = __builtin_amdgcn_mfma_f32_16x16x32_f16(afr[kk], bf, acc[f], 0, 0, 0);
            }
        }
        const float* bb = bs[jw];
        if (jw == 0) {
            #pragma unroll
            for (int f = 0; f < 8; f++) {
                int col = f * 16 + mr;
                float bias = bb[col];
                #pragma unroll
                for (int r = 0; r < 4; r++) {
                    int row = row0 + w * 16 + g * 4 + r;
                    if (row < M) out[(size_t)row * 128 + col] = acc[f][r] + bias;
                }
            }
        } else {
            unsigned char* kvb = kv8 + (size_t)(jw - 1) * 128;
            #pragma unroll
            for (int f = 0; f < 8; f++) {
                int col = f * 16 + mr;
                float bias = bb[col];
                #pragma unroll
                for (int r = 0; r < 4; r++) {
                    int row = row0 + w * 16 + g * 4 + r;   // uniform across mr-pairs
                    float vf = acc[f][r] + bias;
                    float nb = __shfl_xor(vf, 1, 64);
                    if (((mr & 1) == 0) && row < M) {
                        int pw = __builtin_amdgcn_cvt_pk_fp8_f32(vf, nb, 0, false);
                        *(unsigned short*)(kvb + ((size_t)row << 8) + col) = (unsigned short)pw;
                    }
                }
            }
        }
    }
}

// ---------------- Wa GEMM: c-side MFMA fp16, v-side fp32 vector ---------------
__global__ __launch_bounds__(256) void gemm128(
    int nblk1,
    // primary (c-side, MFMA)
    const float* __restrict__ A1, int lda1, const _Float16* __restrict__ W1h,
    const float* __restrict__ bias1, float* __restrict__ out1, int M1,
    const float* __restrict__ gate1, const float* __restrict__ xold1,
    const float* __restrict__ wk1, const float* __restrict__ bk1, float* __restrict__ ko1,
    const float* __restrict__ wv1, const float* __restrict__ bv1, float* __restrict__ vo1,
    // secondary (v-side, fp32 vector)
    const float* __restrict__ A2, int lda2, const float* __restrict__ W2,
    const float* __restrict__ bias2, float* __restrict__ out2, int M2,
    const float* __restrict__ gate2, const float* __restrict__ xold2,
    const float* __restrict__ wk2, const float* __restrict__ bk2, float* __restrict__ ko2)
{
    extern __shared__ char dynsm[];
    int tid = threadIdx.x;

    if ((int)blockIdx.x < nblk1) {
        // ======================= c-side: MFMA =======================
        _Float16 (*Af)[136] = (_Float16(*)[136])dynsm;
        int row0 = blockIdx.x * 64;
        #pragma unroll
        for (int i = 0; i < 8; i++) {
            int slot = tid + i * 256;
            int r = slot >> 5, q = slot & 31;
            int rr = row0 + r;
            float4 v = make_float4(0.f, 0.f, 0.f, 0.f);
            if (rr < M1) v = *(const float4*)(A1 + (size_t)rr * lda1 + q * 4);
            f16x4 h = { (_Float16)v.x, (_Float16)v.y, (_Float16)v.z, (_Float16)v.w };
            *(f16x4*)&Af[r][q * 4] = h;
        }
        __syncthreads();

        int lane = tid & 63, w = tid >> 6;
        int mr = lane & 15, g = lane >> 4;
        f16x8 afr[4];
        #pragma unroll
        for (int kk = 0; kk < 4; kk++)
            afr[kk] = *(const f16x8*)&Af[w * 16 + mr][kk * 32 + g * 8];

        f32x4 acc[8] = {};
        #pragma unroll
        for (int kk = 0; kk < 4; kk++) {
            #pragma unroll
            for (int f = 0; f < 8; f++) {
                f16x8 bf = *(const f16x8*)(W1h + (size_t)(f * 16 + mr) * CH + kk * 32 + g * 8);
                acc[f] = __builtin_amdgcn_mfma_f32_16x16x32_f16(afr[kk], bf, acc[f], 0, 0, 0);
            }
        }

        float gt = 1.f / (1.f + expf(-gate1[0]));
        float og = 1.f - gt;
        float pk[4] = {}, pv[4] = {};
        #pragma unroll
        for (int f = 0; f < 8; f++) {
            int col = f * 16 + mr;
            float bias = bias1[col];
            float wkc = wk1[col];
            float wvc = wv1[col];
            #pragma unroll
            for (int r = 0; r < 4; r++) {
                int row = row0 + w * 16 + g * 4 + r;
                if (row < M1) {
                    float v = acc[f][r] + bias;
                    v = gt * v + og * xold1[(size_t)row * 128 + col];
                    out1[(size_t)row * 128 + col] = v;
                    pk[r] = fmaf(v, wkc, pk[r]);
                    pv[r] = fmaf(v, wvc, pv[r]);
                }
            }
        }
        #pragma unroll
        for (int r = 0; r < 4; r++) {
            #pragma unroll
            for (int off = 1; off < 16; off <<= 1) {
                pk[r] += __shfl_xor(pk[r], off, 64);
                pv[r] += __shfl_xor(pv[r], off, 64);
            }
        }
        if (mr == 0) {
            #pragma unroll
            for (int r = 0; r < 4; r++) {
                int row = row0 + w * 16 + g * 4 + r;
                if (row < M1) {
                    ko1[row] = pk[r] + bk1[0];
                    vo1[row] = pv[r] + bv1[0];
                }
            }
        }
        return;
    }

    // ======================= v-side: fp32 vector =======================
    float (*As)[36]  = (float(*)[36])dynsm;                 // 9216 B
    float (*Bs)[128] = (float(*)[128])(dynsm + 64 * 36 * 4); // 16384 B
    const float* A    = A2;
    int lda           = lda2;
    const float* W    = W2;
    const float* bias = bias2;
    float* out        = out2;
    int M             = M2;
    const float* gate = gate2;
    const float* xold = xold2;
    const float* wk_o = wk2;
    const float* bk_o = bk2;
    float* ko         = ko2;

    int row0 = (blockIdx.x - nblk1) * 64;
    int tx = tid & 15;
    int ty = tid >> 4;
    float acc[4][8] = {};
    for (int k0 = 0; k0 < 128; k0 += 32) {
        __syncthreads();
        #pragma unroll
        for (int i = 0; i < 2; i++) {
            int slot = tid + i * 256;            // [0,512) float4 slots
            int r = slot >> 3, kq = slot & 7;
            int rr = row0 + r;
            float4 v = make_float4(0.f, 0.f, 0.f, 0.f);
            if (rr < M) v = *(const float4*)(A + (size_t)rr * lda + k0 + kq * 4);
            *(float4*)&As[r][kq * 4] = v;
        }
        #pragma unroll
        for (int i = 0; i < 4; i++) {
            int slot = tid + i * 256;            // [0,1024)
            int kr = slot >> 5, cq = slot & 31;
            *(float4*)&Bs[kr][cq * 4] = *(const float4*)(W + (size_t)(k0 + kr) * 128 + cq * 4);
        }
        __syncthreads();
        #pragma unroll
        for (int k4 = 0; k4 < 32; k4 += 4) {
            float4 av[4];
            #pragma unroll
            for (int i = 0; i < 4; i++)
                av[i] = *(const float4*)&As[ty * 4 + i][k4];
            #pragma unroll
            for (int kk = 0; kk < 4; kk++) {
                float4 bl = *(const float4*)&Bs[k4 + kk][tx * 4];
                float4 bh = *(const float4*)&Bs[k4 + kk][64 + tx * 4];
                float bb[8] = {bl.x, bl.y, bl.z, bl.w, bh.x, bh.y, bh.z, bh.w};
                #pragma unroll
                for (int i = 0; i < 4; i++) {
                    float a = ((const float*)&av[i])[kk];
                    #pragma unroll
                    for (int j = 0; j < 8; j++)
                        acc[i][j] = fmaf(a, bb[j], acc[i][j]);
                }
            }
        }
    }
    float gt = 1.f / (1.f + expf(-gate[0]));
    float og = 1.f - gt;
    float wkr[8];
    #pragma unroll
    for (int j = 0; j < 4; j++) {
        wkr[j]     = wk_o[tx * 4 + j];
        wkr[4 + j] = wk_o[64 + tx * 4 + j];
    }
    #pragma unroll
    for (int i = 0; i < 4; i++) {
        int r = row0 + ty * 4 + i;
        if (r >= M) continue;   // uniform across each 16-lane group
        float vals[8];
        #pragma unroll
        for (int j = 0; j < 4; j++) {
            float v0 = acc[i][j]     + bias[tx * 4 + j];
            float v1 = acc[i][4 + j] + bias[64 + tx * 4 + j];
            v0 = gt * v0 + og * xold[(size_t)r * 128 + tx * 4 + j];
            v1 = gt * v1 + og * xold[(size_t)r * 128 + 64 + tx * 4 + j];
            vals[j] = v0;
            vals[4 + j] = v1;
        }
        float* op = out + (size_t)r * 128;
        *(float4*)(op + tx * 4)      = make_float4(vals[0], vals[1], vals[2], vals[3]);
        *(float4*)(op + 64 + tx * 4) = make_float4(vals[4], vals[5], vals[6], vals[7]);
        float pk = 0.f;
        #pragma unroll
        for (int j = 0; j < 8; j++) pk = fmaf(vals[j], wkr[j], pk);
        #pragma unroll
        for (int off = 1; off < 16; off <<= 1)
            pk += __shfl_xor(pk, off, 64);
        if (tx == 0) ko[r] = pk + bk_o[0];
    }
}

// ---------------- pipelined fp8-payload edge accumulation ---------------------
// Per 64-edge chunk: one wave-coalesced csr load, indices via shfl; each edge's
// k+v is 256 B contiguous fp8 (two 128 B lines). HW cvt_pk_f32_fp8 decode.
// Register-double-buffered 2-round pipeline; clamped tail loads masked via w=0.
__device__ __forceinline__ void gather_pipe(
    const unsigned char* __restrict__ kv8, const int* __restrict__ csr,
    int e0, int e1, int g, int j, const float* q8,
    float& s_io, float acc[8])
{
    int lane = threadIdx.x & 63;
    float s = s_io;
    for (int cs = e0; cs < e1; cs += 64) {
        int n = e1 - cs; if (n > 64) n = 64;
        int nm1 = n - 1;
        int idx0 = 0;
        if (lane < n) idx0 = csr[cs + lane];
        int R = (n + 7) >> 3;   // rounds of 8 edges (2 per group)

        uint2 ak0, av0, ak1, av1;   // buffer A (even rounds, 2 edges)
        uint2 bk0, bv0, bk1, bv1;   // buffer B (odd rounds)

#define LD2(E0_, E1_, K0, V0, K1, V1) { \
            int i0_ = __shfl(idx0, min((E0_), nm1), 64); \
            int i1_ = __shfl(idx0, min((E1_), nm1), 64); \
            const unsigned char* p0_ = kv8 + ((size_t)i0_ << 8) + 8 * j; \
            const unsigned char* p1_ = kv8 + ((size_t)i1_ << 8) + 8 * j; \
            K0 = *(const uint2*)p0_; V0 = *(const uint2*)(p0_ + 128); \
            K1 = *(const uint2*)p1_; V1 = *(const uint2*)(p1_ + 128); }

#define CMP(E0_, E1_, K0, V0, K1, V1) { \
            float k0f[8], k1f[8], v0f[8], v1f[8]; \
            fp8x8_to_f32(K0, k0f); fp8x8_to_f32(K1, k1f); \
            float d0_ = dot8f(q8, k0f); \
            float d1_ = dot8f(q8, k1f); \
            d0_ += __shfl_xor(d0_, 1, 64); d1_ += __shfl_xor(d1_, 1, 64); \
            d0_ += __shfl_xor(d0_, 2, 64); d1_ += __shfl_xor(d1_, 2, 64); \
            float w0_ = ((E0_) < n) ? __expf(d0_) : 0.f; \
            float w1_ = ((E1_) < n) ? __expf(d1_) : 0.f; \
            s += w0_ + w1_; \
            fp8x8_to_f32(V0, v0f); fp8x8_to_f32(V1, v1f); \
            acc[0] = fmaf(w0_, v0f[0], acc[0]); acc[0] = fmaf(w1_, v1f[0], acc[0]); \
            acc[1] = fmaf(w0_, v0f[1], acc[1]); acc[1] = fmaf(w1_, v1f[1], acc[1]); \
            acc[2] = fmaf(w0_, v0f[2], acc[2]); acc[2] = fmaf(w1_, v1f[2], acc[2]); \
            acc[3] = fmaf(w0_, v0f[3], acc[3]); acc[3] = fmaf(w1_, v1f[3], acc[3]); \
            acc[4] = fmaf(w0_, v0f[4], acc[4]); acc[4] = fmaf(w1_, v1f[4], acc[4]); \
            acc[5] = fmaf(w0_, v0f[5], acc[5]); acc[5] = fmaf(w1_, v1f[5], acc[5]); \
            acc[6] = fmaf(w0_, v0f[6], acc[6]); acc[6] = fmaf(w1_, v1f[6], acc[6]); \
            acc[7] = fmaf(w0_, v0f[7], acc[7]); acc[7] = fmaf(w1_, v1f[7], acc[7]); }

        // prefetch round 0 (A) and round 1 (B)
        LD2(g, g + 4, ak0, av0, ak1, av1);
        if (R > 1) LD2(g + 8, g + 12, bk0, bv0, bk1, bv1);

        for (int r = 0; r < R; r += 2) {
            int er = g + 8 * r;
            CMP(er, er + 4, ak0, av0, ak1, av1);
            if (r + 2 < R) {
                int ep = g + 8 * (r + 2);
                LD2(ep, ep + 4, ak0, av0, ak1, av1);
            }
            if (r + 1 < R) {
                int eo = g + 8 * (r + 1);
                CMP(eo, eo + 4, bk0, bv0, bk1, bv1);
                if (r + 3 < R) {
                    int eq = g + 8 * (r + 3);
                    LD2(eq, eq + 4, bk0, bv0, bk1, bv1);
                }
            }
        }
#undef LD2
#undef CMP
    }
    s_io = s;
}

// ---------------- unified attention: cv blocks [0,256) + cc blocks -------------
__global__ __launch_bounds__(256) void attn_uni(
    float* xq, const unsigned char* __restrict__ kv8,
    const float* __restrict__ xv, const float* __restrict__ wqt,
    const float* __restrict__ bqt,
    const int* __restrict__ rs_cc, const int* __restrict__ csr_cc,
    const int* __restrict__ rs_cv, const int* __restrict__ csr_cv,
    const float* __restrict__ mrel_cc, const float* __restrict__ mrel_cv,
    float* __restrict__ aggv, int n_c)
{
    __shared__ float smem[800];   // 3.2 KB, carved per role
    int lane = threadIdx.x & 63, wid = threadIdx.x >> 6;
    int g = lane >> 4, j = lane & 15;

    if (blockIdx.x < N_V) {
        // ---------------- cv node ----------------
        int node = blockIdx.x;
        float* qrow = smem;          // [128]
        float* sm_s = smem + 128;    // [4][4]
        float* sm_a = smem + 144;    // [4][128]
        float* orow = smem + 656;    // [144]
        if (wid < 2) {
            int col = wid * 64 + lane;
            float a = bqt[col];
            const float* xr = xv + (size_t)node * 128;
            for (int k = 0; k < 128; k++)
                a = fmaf(xr[k], wqt[(size_t)k * 128 + col], a);
            qrow[col] = a;
        }
        __syncthreads();
        float q8[8];
        *(float4*)&q8[0] = *(const float4*)&qrow[8 * j];
        *(float4*)&q8[4] = *(const float4*)&qrow[8 * j + 4];
        int rs = rs_cv[node], re = rs_cv[node + 1];
        int cnt = re - rs;
        int per = (cnt + 3) >> 2;
        int e0 = rs + wid * per, e1 = min(e0 + per, re);
        float s = 0.f;
        float acc[8] = {};
        gather_pipe(kv8, csr_cv, e0, e1, g, j, q8, s, acc);
        #pragma unroll
        for (int i = 0; i < 8; i++) {
            acc[i] += __shfl_xor(acc[i], 16, 64);
            acc[i] += __shfl_xor(acc[i], 32, 64);
        }
        s += __shfl_xor(s, 16, 64);
        s += __shfl_xor(s, 32, 64);
        if (g == 0) {
            *(float4*)&sm_a[wid * 128 + 8 * j]     = make_float4(acc[0], acc[1], acc[2], acc[3]);
            *(float4*)&sm_a[wid * 128 + 8 * j + 4] = make_float4(acc[4], acc[5], acc[6], acc[7]);
            if ((j & 3) == 0) sm_s[wid * 4 + (j >> 2)] = s;
        }
        __syncthreads();
        if (threadIdx.x < 64) {
            int lp = 2 * lane;
            int h = lp >> 5;
            float S = 0.f, AX = 0.f, AY = 0.f;
            #pragma unroll
            for (int i = 0; i < 4; i++) {
                S  += sm_s[i * 4 + h];
                float2 a2 = *(const float2*)&sm_a[i * 128 + lp];
                AX += a2.x;
                AY += a2.y;
            }
            float inv = (S > 0.f) ? 1.f / S : 0.f;
            int off = lp + 4 * h;   // padded
            orow[off]     = AX * inv;
            orow[off + 1] = AY * inv;
            int eo = lp & 31;
            const float* mr = mrel_cv + h * 1024 + eo;
            const float* rb = orow + 36 * h;
            float t0 = 0.f, t1 = 0.f;
            #pragma unroll
            for (int d = 0; d < 32; d++) {
                float a = rb[d];
                t0 = fmaf(a, mr[d * 32], t0);
                t1 = fmaf(a, mr[d * 32 + 1], t1);
            }
            aggv[(size_t)node * 128 + lp]     = gelu_tanh(t0);
            aggv[(size_t)node * 128 + lp + 1] = gelu_tanh(t1);
        }
    } else {
        // ---------------- cc nodes (4 per block, 1 wave each) ----------------
        float* rowbuf = smem;        // [4][144]
        int node = (blockIdx.x - N_V) * 4 + wid;
        if (node >= n_c) return;
        const float* qp = xq + (size_t)node * 128 + 8 * j;
        float q8[8];
        *(float4*)&q8[0] = *(const float4*)qp;
        *(float4*)&q8[4] = *(const float4*)(qp + 4);
        int rs = rs_cc[node], re = rs_cc[node + 1];
        float s = 0.f;
        float acc[8] = {};
        gather_pipe(kv8, csr_cc, rs, re, g, j, q8, s, acc);
        #pragma unroll
        for (int i = 0; i < 8; i++) {
            acc[i] += __shfl_xor(acc[i], 16, 64);
            acc[i] += __shfl_xor(acc[i], 32, 64);
        }
        s += __shfl_xor(s, 16, 64);
        s += __shfl_xor(s, 32, 64);
        float inv = (s > 0.f) ? 1.f / s : 0.f;
        float* rb_w = rowbuf + wid * 144;
        if (g == 0) {
            int off = 8 * j + 4 * (j >> 2);   // +4 pad per head
            float4 o0 = make_float4(acc[0] * inv, acc[1] * inv, acc[2] * inv, acc[3] * inv);
            float4 o1 = make_float4(acc[4] * inv, acc[5] * inv, acc[6] * inv, acc[7] * inv);
            *(float4*)&rb_w[off]     = o0;
            *(float4*)&rb_w[off + 4] = o1;
        }
        // intra-wave DS ordering: no barrier needed
        int lp = 2 * lane;
        int h = lp >> 5, eo = lp & 31;
        const float* mr = mrel_cc + h * 1024 + eo;
        const float* rb = rb_w + 36 * h;
        float t0 = 0.f, t1 = 0.f;
        #pragma unroll
        for (int d = 0; d < 32; d++) {
            float a = rb[d];
            t0 = fmaf(a, mr[d * 32], t0);
            t1 = fmaf(a, mr[d * 32 + 1], t1);
        }
        float2 o = make_float2(gelu_tanh(t0), gelu_tanh(t1));
        *(float2*)(xq + (size_t)node * 128 + lp) = o;
    }
}

// ---------------- out-conv scalar attention (standalone, last layer) -----------
__global__ __launch_bounds__(256) void attn_out(
    const float* __restrict__ qo, const float* __restrict__ ko, const float* __restrict__ vo,
    const int* __restrict__ rowstart, const int* __restrict__ csr,
    const float* __restrict__ arel_o, const float* __restrict__ prel_o,
    const float* __restrict__ mrel_o, const float* __restrict__ Wa_o,
    const float* __restrict__ ba_o, float* __restrict__ outl)
{
    int node = blockIdx.x;
    float qs = qo[node] * arel_o[0] * prel_o[0];
    int rs = rowstart[node], re = rowstart[node + 1];
    float s = 0.f, a = 0.f;
    for (int e = rs + (int)threadIdx.x; e < re; e += 256) {
        int si = csr[e];
        float w = __expf(qs * ko[si]);
        s += w;
        a = fmaf(w, vo[si], a);
    }
    #pragma unroll
    for (int off = 32; off >= 1; off >>= 1) {
        s += __shfl_xor(s, off, 64);
        a += __shfl_xor(a, off, 64);
    }
    __shared__ float sms[4], sma[4];
    int lane = threadIdx.x & 63, wid = threadIdx.x >> 6;
    if (lane == 0) { sms[wid] = s; sma[wid] = a; }
    __syncthreads();
    if (threadIdx.x == 0) {
        float S = sms[0] + sms[1] + sms[2] + sms[3];
        float A = sma[0] + sma[1] + sma[2] + sma[3];
        float agg = (S > 0.f) ? A / S : 0.f;
        agg *= mrel_o[0];
        outl[node] = gelu_tanh(agg) * Wa_o[0] + ba_o[0];
    }
}

// ---------------- final head: JK-max -> node_fc -> MLP ------------------------
__global__ void final_head(const float* __restrict__ outs,
    const float* __restrict__ fc_W, const float* __restrict__ fc_b,
    const float* __restrict__ W1, const float* __restrict__ b1,
    const float* __restrict__ W2, const float* __restrict__ b2,
    float* __restrict__ out)
{
    int b = threadIdx.x;
    if (b >= 64) return;
    float h = fc_b[0];
    #pragma unroll
    for (int v = 0; v < 4; v++) {
        int n = b * 4 + v;
        float jk = fmaxf(fmaxf(outs[0 * N_V + n], outs[1 * N_V + n]), outs[2 * N_V + n]);
        h = fmaf(jk, fc_W[v], h);
    }
    h = gelu_tanh(h);
    float h0 = gelu_tanh(h * W1[0] + b1[0]);
    float h1 = gelu_tanh(h * W1[1] + b1[1]);
    out[b] = h0 * W2[0] + h1 * W2[1] + b2[0];
}

// ---------------- orchestration ----------------------------------------------
extern "C" void kernel_launch(void* const* d_in, const int* in_sizes, int n_in,
                              void* d_out, int out_size, void* d_ws, size_t ws_size,
                              hipStream_t stream) {
    (void)in_sizes; (void)n_in; (void)out_size; (void)ws_size;
    const float* x_cell  = (const float*)d_in[0];
    const float* x_vcell = (const float*)d_in[1];
    const float* Wk   = (const float*)d_in[2];
    const float* bk   = (const float*)d_in[3];
    const float* Wq   = (const float*)d_in[4];
    const float* bq   = (const float*)d_in[5];
    const float* Wv   = (const float*)d_in[6];
    const float* bv   = (const float*)d_in[7];
    const float* Wa   = (const float*)d_in[8];
    const float* ba   = (const float*)d_in[9];
    const float* skip = (const float*)d_in[10];
    const float* arel = (const float*)d_in[11];
    const float* mrel = (const float*)d_in[12];
    const float* prel = (const float*)d_in[13];
    const float* Wk_o = (const float*)d_in[14];
    const float* bk_o = (const float*)d_in[15];
    const float* Wq_o = (const float*)d_in[16];
    const float* bq_o = (const float*)d_in[17];
    const float* Wv_o = (const float*)d_in[18];
    const float* bv_o = (const float*)d_in[19];
    const float* Wa_o = (const float*)d_in[20];
    const float* ba_o = (const float*)d_in[21];
    const float* arel_o = (const float*)d_in[22];
    const float* mrel_o = (const float*)d_in[23];
    const float* prel_o = (const float*)d_in[24];
    const float* fc_W  = (const float*)d_in[25];
    const float* fc_b  = (const float*)d_in[26];
    const float* mlp_W1 = (const float*)d_in[27];
    const float* mlp_b1 = (const float*)d_in[28];
    const float* mlp_W2 = (const float*)d_in[29];
    const float* mlp_b2 = (const float*)d_in[30];
    const int* src_cc = (const int*)d_in[31];
    const int* dst_cc = (const int*)d_in[32];
    const int* src_cv = (const int*)d_in[33];
    const int* dst_cv = (const int*)d_in[34];

    // workspace carve-up (256B aligned)
    char* p = (char*)d_ws;
    auto alloc = [&](size_t bytes) -> char* {
        uintptr_t q = ((uintptr_t)p + 255) & ~(uintptr_t)255;
        p = (char*)(q + bytes);
        return (char*)q;
    };
    float* WQT  = (float*)alloc(sizeof(float) * NL * 2 * CH * CH);
    float* BQT  = (float*)alloc(sizeof(float) * NL * 2 * CH);
    _Float16* WT16 = (_Float16*)alloc(sizeof(_Float16) * NL * 4 * CH * CH);
    float* XC   = (float*)alloc(sizeof(float) * (size_t)N_C * CH);
    float* XV   = (float*)alloc(sizeof(float) * (size_t)N_V * CH);
    float* XQ   = (float*)alloc(sizeof(float) * (size_t)N_C * CH);  // q~ / agg
    unsigned char* KV8 = (unsigned char*)alloc((size_t)N_C * 256);  // k,v fp8
    float* AGGV = (float*)alloc(sizeof(float) * (size_t)N_V * CH);
    float* KO   = (float*)alloc(sizeof(float) * N_C);
    float* VO   = (float*)alloc(sizeof(float) * N_C);
    float* QO   = (float*)alloc(sizeof(float) * N_V);
    float* OUTS = (float*)alloc(sizeof(float) * NL * N_V);
    // CSR-build scratch (hist region zeroed in one memset)
    int* bhist    = (int*)alloc(sizeof(int) * 512);
    int* bhist_cc = bhist;
    int* bhist_cv = bhist + 256;
    int* bbase_cc = (int*)alloc(sizeof(int) * 257);
    int* cur_cc   = (int*)alloc(sizeof(int) * 256);
    int* cur_cv   = (int*)alloc(sizeof(int) * 256);
    int* rs_cc    = (int*)alloc(sizeof(int) * (N_C + 1));
    int* rs_cv    = (int*)alloc(sizeof(int) * (N_V + 1));
    int* csr_cc   = (int*)alloc(sizeof(int) * NE1);
    int* csr_cv   = (int*)alloc(sizeof(int) * NE2);
    int2* tmp_cc  = (int2*)alloc(sizeof(int2) * NE1);

    // ---- setup: composed weights + fp16 weights + CSR ----
    compose_wq<<<CDIV(NL * 2 * (CH + 1) * CH, 256), 256, 0, stream>>>(
        Wq, bq, arel, prel, WQT, BQT);
    cvt_w16<<<NL * 4, 128, 0, stream>>>(WQT, Wk, Wv, Wa, WT16);
    hipMemsetAsync(bhist, 0, sizeof(int) * 512, stream);
    bucket_hist<<<CDIV(NE1, EPB), 256, 0, stream>>>(dst_cc, NE1, 8, bhist_cc);
    bucket_hist<<<CDIV(NE2, EPB), 256, 0, stream>>>(dst_cv, NE2, 0, bhist_cv);
    scan256<<<1, 256, 0, stream>>>(bhist_cc, bbase_cc, cur_cc);
    scan256<<<1, 256, 0, stream>>>(bhist_cv, rs_cv, cur_cv);   // rs_cv IS the cv row starts
    partition_edges<true ><<<CDIV(NE1, EPB), 256, 0, stream>>>(src_cc, dst_cc, NE1, 8,
                                                               cur_cc, tmp_cc, nullptr);
    partition_edges<false><<<CDIV(NE2, EPB), 256, 0, stream>>>(src_cv, dst_cv, NE2, 0,
                                                               cur_cv, nullptr, csr_cv);
    bucket_finalize<<<CDIV(N_C, 256), 256, 0, stream>>>(tmp_cc, bbase_cc, N_C, NE1,
                                                        rs_cc, csr_cc);

    const int gb_c = CDIV(N_C, 64);             // 938
    const int gb_v = CDIV(N_V, 64);             // 4
    const int gb_attn = N_V + CDIV(N_C, 4);     // 256 cv + 15000 cc blocks
    const int SM_QKV = 64 * 136 * 2;            // 17408 B
    const int SM_128 = 64 * 36 * 4 + 32 * 128 * 4;  // 25600 B (>= MFMA's 17408)

    for (int li = 0; li < NL; li++) {
        const float* xc_src = (li == 0) ? x_cell : XC;
        const float* xv_src = (li == 0) ? x_vcell : XV;
        size_t w1 = (size_t)(li * 2 + 1) * CH * CH;
        int b0 = (li * 2) * CH, b1 = (li * 2 + 1) * CH;
        const _Float16* WT_qkv = WT16 + (size_t)(li * 4) * CH * CH;      // q~,k,v
        const _Float16* WT_a   = WT16 + (size_t)(li * 4 + 3) * CH * CH;  // Wa c-side

        // fused q~/k/v MFMA GEMM; layers >0 append prev-layer out-conv attn tail
        int tail = (li > 0) ? N_V : 0;
        gemm_qkv<<<gb_c + tail, 256, SM_QKV, stream>>>(
            gb_c, xc_src, 128, N_C,
            WT_qkv,
            BQT + b0, bk + b0, bv + b0, XQ, KV8,
            QO, KO, VO, rs_cv, csr_cv,
            arel_o + (li - 1), prel_o + (li - 1), mrel_o + (li - 1),
            Wa_o + (li - 1), ba_o + (li - 1),
            (li > 0) ? (OUTS + (li - 1) * N_V) : nullptr);

        // unified attention: cv (inline q~v projection, 4 waves/node) + cc
        attn_uni<<<gb_attn, 256, 0, stream>>>(
            XQ, KV8, xv_src, WQT + w1, BQT + b1,
            rs_cc, csr_cc, rs_cv, csr_cv,
            mrel + (size_t)(li * 2) * NH * HD * HD,
            mrel + (size_t)(li * 2 + 1) * NH * HD * HD,
            AGGV, N_C);

        // merged Wa GEMMs (c-side MFMA + v-side vector) with skip epilogue;
        // c-side fuses out-conv k/v projections, v-side fuses q projection
        gemm128<<<gb_c + gb_v, 256, SM_128, stream>>>(
            gb_c,
            XQ, 128, WT_a, ba + b0, XC, N_C,
            skip + li * 2, xc_src,
            Wk_o + li * CH, bk_o + li, KO,
            Wv_o + li * CH, bv_o + li, VO,
            AGGV, 128, Wa + w1, ba + b1, XV, N_V,
            skip + li * 2 + 1, xv_src,
            Wq_o + li * CH, bq_o + li, QO);
    }

    // last layer's out-conv attention, then final head
    attn_out<<<N_V, 256, 0, stream>>>(QO, KO, VO, rs_cv, csr_cv,
                                      arel_o + (NL - 1), prel_o + (NL - 1), mrel_o + (NL - 1),
                                      Wa_o + (NL - 1), ba_o + (NL - 1), OUTS + (NL - 1) * N_V);
    final_head<<<1, 64, 0, stream>>>(OUTS, fc_W, fc_b, mlp_W1, mlp_b1, mlp_W2, mlp_b2,
                                     (float*)d_out);
}